// Round 1
// baseline (3001.737 us; speedup 1.0000x reference)
//
#include <hip/hip_runtime.h>
#include <math.h>

// ---------------------------------------------------------------------------
// EquiformerPointHead — fp32 reference-faithful implementation.
// N=10000, D_IN=256, C0=256, C1=64, DEPTH=4, HEADS=4, DH=32, H=128, K=16, R=16
// Key restructuring: projections computed per-node then gathered
// ((f0n @ W)[idx] == f0n[idx] @ W), cutting ~3x the reference FLOPs.
// f1 / V1 / O1 stored component-major: (N, 3, C) rows of length C.
// ---------------------------------------------------------------------------

#define NPTS 10000
#define C0v 256
#define C1v 64
#define Hv 128
#define Kv 16
#define Rv 16

struct BP4 { const float* p[4]; };

__device__ __forceinline__ float gelu_f(float x) {
    float u = 0.7978845608028654f * (x + 0.044715f * x * x * x);
    return 0.5f * x * (1.0f + tanhf(u));
}
__device__ __forceinline__ float sigmoid_f(float x) {
    return 1.0f / (1.0f + expf(-x));
}

// ---------------------------------------------------------------------------
// Tiled fp32 GEMM: C[M x N] = epi(A[M x Kc] @ B[Kc x N]).
// BM=128, BN=64, BK=16, 256 threads, 8x4 micro-tile.
// ACT: 0 none, 1 gelu, 2 sigmoid.  ADD: C += ...  BIAS: +bias[col]
// GATED: scale by gate[row/3][col] before ADD.  SEG: 4 B-segments of width 128.
// ---------------------------------------------------------------------------
template<int ACT, bool ADD, bool BIAS, bool GATED, bool SEG>
__global__ __launch_bounds__(256)
void gemm_k(BP4 bp, int ldb,
            const float* __restrict__ bias,
            const float* __restrict__ gate,
            const float* __restrict__ A, int lda,
            float* __restrict__ C, int ldc,
            int M, int Kc)
{
    __shared__ float As[16][132];
    __shared__ float Bs[16][68];
    const int bm = blockIdx.y * 128;
    const float* B;
    int bnB, bnC;
    if (SEG) {
        B = bp.p[blockIdx.x >> 1];
        bnB = (blockIdx.x & 1) * 64;
        bnC = blockIdx.x * 64;
    } else {
        B = bp.p[0];
        bnB = blockIdx.x * 64;
        bnC = bnB;
    }
    const int tid = threadIdx.x;
    const int tx = tid & 15, ty = tid >> 4;
    const int ar = tid >> 2, ac = (tid & 3) * 4;   // A tile: rows ar, ar+64; cols ac..ac+3
    const int br = tid >> 4, bc = (tid & 15) * 4;  // B tile

    float acc[8][4] = {};

    for (int kt = 0; kt < Kc; kt += 16) {
        float4 a0 = make_float4(0.f, 0.f, 0.f, 0.f);
        float4 a1 = make_float4(0.f, 0.f, 0.f, 0.f);
        if (bm + ar < M)      a0 = *(const float4*)(A + (size_t)(bm + ar) * lda + kt + ac);
        if (bm + ar + 64 < M) a1 = *(const float4*)(A + (size_t)(bm + ar + 64) * lda + kt + ac);
        float4 bv = *(const float4*)(B + (size_t)(kt + br) * ldb + bnB + bc);
        As[ac + 0][ar] = a0.x; As[ac + 1][ar] = a0.y; As[ac + 2][ar] = a0.z; As[ac + 3][ar] = a0.w;
        As[ac + 0][ar + 64] = a1.x; As[ac + 1][ar + 64] = a1.y; As[ac + 2][ar + 64] = a1.z; As[ac + 3][ar + 64] = a1.w;
        *(float4*)&Bs[br][bc] = bv;
        __syncthreads();
        #pragma unroll
        for (int kk = 0; kk < 16; ++kk) {
            float4 bq  = *(const float4*)&Bs[kk][tx * 4];
            float4 aq0 = *(const float4*)&As[kk][ty * 8];
            float4 aq1 = *(const float4*)&As[kk][ty * 8 + 4];
            float a8[8] = {aq0.x, aq0.y, aq0.z, aq0.w, aq1.x, aq1.y, aq1.z, aq1.w};
            float b4[4] = {bq.x, bq.y, bq.z, bq.w};
            #pragma unroll
            for (int i = 0; i < 8; ++i)
                #pragma unroll
                for (int j = 0; j < 4; ++j)
                    acc[i][j] += a8[i] * b4[j];
        }
        __syncthreads();
    }

    #pragma unroll
    for (int i = 0; i < 8; ++i) {
        int row = bm + ty * 8 + i;
        if (row < M) {
            int col = bnC + tx * 4;
            float4 v = make_float4(acc[i][0], acc[i][1], acc[i][2], acc[i][3]);
            if (BIAS) {
                const float* bb = bias + col;
                v.x += bb[0]; v.y += bb[1]; v.z += bb[2]; v.w += bb[3];
            }
            if (ACT == 1) { v.x = gelu_f(v.x); v.y = gelu_f(v.y); v.z = gelu_f(v.z); v.w = gelu_f(v.w); }
            if (ACT == 2) { v.x = sigmoid_f(v.x); v.y = sigmoid_f(v.y); v.z = sigmoid_f(v.z); v.w = sigmoid_f(v.w); }
            if (GATED) {
                const float* gp = gate + (size_t)(row / 3) * 64 + col;
                v.x *= gp[0]; v.y *= gp[1]; v.z *= gp[2]; v.w *= gp[3];
            }
            float* cp = C + (size_t)row * ldc + col;
            if (ADD) {
                float4 c0 = *(const float4*)cp;
                v.x += c0.x; v.y += c0.y; v.z += c0.z; v.w += c0.w;
            }
            *(float4*)cp = v;
        }
    }
}

// ---------------------------------------------------------------------------
// LayerNorm over rows of 256. One wave per row, 4 rows per 256-thread block.
// ---------------------------------------------------------------------------
__global__ __launch_bounds__(256)
void ln_k(const float* __restrict__ x, float* __restrict__ y, int M)
{
    int lane = threadIdx.x & 63;
    int row = blockIdx.x * 4 + (threadIdx.x >> 6);
    if (row >= M) return;
    float4 v = ((const float4*)(x + (size_t)row * 256))[lane];
    float s = v.x + v.y + v.z + v.w;
    #pragma unroll
    for (int m = 32; m >= 1; m >>= 1) s += __shfl_xor(s, m);
    float mean = s * 0.00390625f;
    float dx = v.x - mean, dy = v.y - mean, dz = v.z - mean, dw = v.w - mean;
    float vs = dx * dx + dy * dy + dz * dz + dw * dw;
    #pragma unroll
    for (int m = 32; m >= 1; m >>= 1) vs += __shfl_xor(vs, m);
    float rs = rsqrtf(vs * 0.00390625f + 1e-6f);
    float4 o; o.x = dx * rs; o.y = dy * rs; o.z = dz * rs; o.w = dw * rs;
    ((float4*)(y + (size_t)row * 256))[lane] = o;
}

// ---------------------------------------------------------------------------
// kNN (K=16 smallest d2, self included) + rbf + rel_unit precompute.
// 64 threads/block = 16 queries x 4 candidate-interleave parts.
// d2 computed contract-off in the reference order to match numpy boundaries.
// ---------------------------------------------------------------------------
#define KNN_CHUNK 2048
__global__ __launch_bounds__(64)
void knn_k(const float* __restrict__ coors, int* __restrict__ idxp,
           float* __restrict__ rbfp, float* __restrict__ rup)
{
    #pragma clang fp contract(off)
    __shared__ float cf[KNN_CHUNK * 3];
    __shared__ float mD[16][4][16];
    __shared__ int   mI[16][4][16];
    const int t = threadIdx.x;
    const int qq = t & 15;
    const int part = t >> 4;
    const int n = blockIdx.x * 16 + qq;
    const float qx = coors[n * 3 + 0], qy = coors[n * 3 + 1], qz = coors[n * 3 + 2];

    float bd[16]; int bi[16];
    #pragma unroll
    for (int m = 0; m < 16; ++m) { bd[m] = 3.4e38f; bi[m] = 0; }

    for (int cbase = 0; cbase < NPTS; cbase += KNN_CHUNK) {
        int cn = min(KNN_CHUNK, NPTS - cbase);
        __syncthreads();
        for (int qi = t; qi < cn * 3; qi += 64) cf[qi] = coors[cbase * 3 + qi];
        __syncthreads();
        int nj = cn >> 2;  // cn divisible by 4 (2048, 1808)
        for (int jj = 0; jj < nj; ++jj) {
            int local = jj * 4 + part;
            float dx = cf[local * 3 + 0] - qx;
            float dy = cf[local * 3 + 1] - qy;
            float dz = cf[local * 3 + 2] - qz;
            float d2 = dx * dx + dy * dy;
            d2 = d2 + dz * dz;
            if (d2 < bd[15]) {
                int j = cbase + local;
                #pragma unroll
                for (int m = 15; m >= 1; --m) {
                    bool up = bd[m - 1] > d2;
                    float nd = up ? bd[m - 1] : (bd[m] > d2 ? d2 : bd[m]);
                    int   ni = up ? bi[m - 1] : (bd[m] > d2 ? j : bi[m]);
                    bd[m] = nd; bi[m] = ni;
                }
                if (bd[0] > d2) { bd[0] = d2; bi[0] = j; }
            }
        }
    }
    __syncthreads();
    #pragma unroll
    for (int m = 0; m < 16; ++m) { mD[qq][part][m] = bd[m]; mI[qq][part][m] = bi[m]; }
    __syncthreads();

    if (t < 16) {
        const int nn = blockIdx.x * 16 + t;
        int c0 = 0, c1 = 0, c2 = 0, c3 = 0;
        for (int m = 0; m < 16; ++m) {
            float v0 = mD[t][0][c0], v1 = mD[t][1][c1], v2 = mD[t][2][c2], v3 = mD[t][3][c3];
            float best = v0; int w = 0;
            if (v1 < best) { best = v1; w = 1; }
            if (v2 < best) { best = v2; w = 2; }
            if (v3 < best) { best = v3; w = 3; }
            int j;
            if (w == 0)      { j = mI[t][0][c0]; c0++; }
            else if (w == 1) { j = mI[t][1][c1]; c1++; }
            else if (w == 2) { j = mI[t][2][c2]; c2++; }
            else             { j = mI[t][3][c3]; c3++; }
            idxp[nn * 16 + m] = j;
            float dist = sqrtf(best + 1e-6f);
            float rx = coors[j * 3 + 0] - qx;
            float ry = coors[j * 3 + 1] - qy;
            float rz = coors[j * 3 + 2] - qz;
            rup[(nn * 16 + m) * 3 + 0] = rx / dist;
            rup[(nn * 16 + m) * 3 + 1] = ry / dist;
            rup[(nn * 16 + m) * 3 + 2] = rz / dist;
            #pragma unroll
            for (int r = 0; r < 16; ++r) {
                float c = (4.0f / 15.0f) * r;
                float dd = dist - c;
                rbfp[(size_t)nn * 256 + m * 16 + r] = expf(-dd * dd * 8.0f);
            }
        }
    }
}

// ---------------------------------------------------------------------------
// Fused attention: one block per node, 128 threads (one per channel hd).
// P layout per node: [q(128) | k(128) | v0(128) | vr(128)].
// V1/O1 layout per node: [v=0 (128) | v=1 | v=2].
// ---------------------------------------------------------------------------
__global__ __launch_bounds__(128)
void attn_k(const float* __restrict__ P, const float* __restrict__ V1,
            const float* __restrict__ rbf, const float* __restrict__ ru,
            const int* __restrict__ idx,
            const float* __restrict__ We, const float* __restrict__ Wer,
            float* __restrict__ O0, float* __restrict__ O1)
{
    const int n = blockIdx.x;
    const int hd = threadIdx.x;
    const int h = hd >> 5;
    __shared__ float WeS[16][128], WerS[16][128];
    __shared__ float rbfS[16][16];
    __shared__ float ruS[16][4];
    __shared__ int   idxS[16];
    __shared__ float logitsS[4][16];
    __shared__ float attnS[4][16];

    #pragma unroll
    for (int r = 0; r < 16; ++r) {
        WeS[r][hd]  = We[r * 128 + hd];
        WerS[r][hd] = Wer[r * 128 + hd];
    }
    ((float*)rbfS)[hd]       = rbf[(size_t)n * 256 + hd];
    ((float*)rbfS)[hd + 128] = rbf[(size_t)n * 256 + 128 + hd];
    if (hd < 16) idxS[hd] = idx[n * 16 + hd];
    if (hd < 48) ruS[hd / 3][hd % 3] = ru[n * 48 + hd];
    float q = P[(size_t)n * 512 + hd];
    __syncthreads();

    // pass 1: logits
    #pragma unroll 4
    for (int k = 0; k < 16; ++k) {
        int j = idxS[k];
        float kv = P[(size_t)j * 512 + 128 + hd];
        float racc = 0.f;
        #pragma unroll
        for (int r = 0; r < 16; ++r) racc += rbfS[k][r] * WeS[r][hd];
        kv += racc;
        float prod = q * kv;
        prod += __shfl_xor(prod, 1);
        prod += __shfl_xor(prod, 2);
        prod += __shfl_xor(prod, 4);
        prod += __shfl_xor(prod, 8);
        prod += __shfl_xor(prod, 16);
        if ((hd & 31) == 0) logitsS[h][k] = prod * 0.17677669529663687f;  // 1/sqrt(32)
    }
    __syncthreads();

    // softmax (redundant per-thread over own head's 16 logits)
    {
        float mx = -1e30f;
        #pragma unroll
        for (int k = 0; k < 16; ++k) mx = fmaxf(mx, logitsS[h][k]);
        float aw[16]; float s = 0.f;
        #pragma unroll
        for (int k = 0; k < 16; ++k) { aw[k] = expf(logitsS[h][k] - mx); s += aw[k]; }
        float inv = 1.f / s;
        if ((hd & 31) == 0) {
            #pragma unroll
            for (int k = 0; k < 16; ++k) attnS[h][k] = aw[k] * inv;
        }
    }
    __syncthreads();

    // pass 2: weighted sums
    float o0 = 0.f, o1x = 0.f, o1y = 0.f, o1z = 0.f;
    #pragma unroll 4
    for (int k = 0; k < 16; ++k) {
        int j = idxS[k];
        float a = attnS[h][k];
        const float* pj = P + (size_t)j * 512;
        float v0 = pj[256 + hd];
        float ge = pj[384 + hd];
        float racc = 0.f;
        #pragma unroll
        for (int r = 0; r < 16; ++r) racc += rbfS[k][r] * WerS[r][hd];
        ge += racc;
        const float* vj = V1 + (size_t)j * 384;
        o0  += a * v0;
        o1x += a * (vj[hd]       + ge * ruS[k][0]);
        o1y += a * (vj[128 + hd] + ge * ruS[k][1]);
        o1z += a * (vj[256 + hd] + ge * ruS[k][2]);
    }
    O0[(size_t)n * 128 + hd] = o0;
    float* o1p = O1 + (size_t)n * 384;
    o1p[hd] = o1x; o1p[128 + hd] = o1y; o1p[256 + hd] = o1z;
}

// ---------------------------------------------------------------------------
// pred_vector: out2[n*3+v] = sum_c f1[n][v][c] * wv[c]
// ---------------------------------------------------------------------------
__global__ __launch_bounds__(256)
void vecout_k(const float* __restrict__ f1, const float* __restrict__ wv,
              float* __restrict__ out2)
{
    int row = blockIdx.x * 256 + threadIdx.x;
    if (row >= NPTS * 3) return;
    const float4* fr = (const float4*)(f1 + (size_t)row * 64);
    const float4* w4 = (const float4*)wv;
    float s = 0.f;
    #pragma unroll
    for (int c = 0; c < 16; ++c) {
        float4 a = fr[c], b = w4[c];
        s += a.x * b.x + a.y * b.y + a.z * b.z + a.w * b.w;
    }
    out2[row] = s;
}

// ---------------------------------------------------------------------------
extern "C" void kernel_launch(void* const* d_in, const int* in_sizes, int n_in,
                              void* d_out, int out_size, void* d_ws, size_t ws_size,
                              hipStream_t stream)
{
    (void)in_sizes; (void)n_in; (void)out_size; (void)ws_size;
    const float* feats = (const float*)d_in[0];
    const float* coors = (const float*)d_in[1];
    // d_in[2]: mask — all true, unused
    const float* Wemb = (const float*)d_in[3];
    const float* Wq   = (const float*)d_in[4];
    const float* Wk   = (const float*)d_in[5];
    const float* Wv0  = (const float*)d_in[6];
    const float* Wvr  = (const float*)d_in[7];
    const float* We   = (const float*)d_in[8];
    const float* Wer  = (const float*)d_in[9];
    const float* Wv1  = (const float*)d_in[10];
    const float* Wo0  = (const float*)d_in[11];
    const float* Wo1  = (const float*)d_in[12];
    const float* Wf1  = (const float*)d_in[13];
    const float* bf1  = (const float*)d_in[14];
    const float* Wf2  = (const float*)d_in[15];
    const float* bf2  = (const float*)d_in[16];
    const float* Wg   = (const float*)d_in[17];
    const float* Wvff = (const float*)d_in[18];
    const float* Ws   = (const float*)d_in[19];
    const float* bs   = (const float*)d_in[20];
    const float* wv   = (const float*)d_in[21];
    float* out = (float*)d_out;

    char* ws = (char*)d_ws;
    size_t off = 0;
    auto carve = [&](size_t bytes) -> char* {
        char* p = ws + off;
        off += (bytes + 255) & ~(size_t)255;
        return p;
    };
    int*   idxp = (int*)  carve((size_t)NPTS * 16 * 4);
    float* rbfp = (float*)carve((size_t)NPTS * 256 * 4);
    float* rup  = (float*)carve((size_t)NPTS * 48 * 4);
    float* f0   = (float*)carve((size_t)NPTS * 256 * 4);
    float* f0n  = (float*)carve((size_t)NPTS * 256 * 4);
    float* f1   = (float*)carve((size_t)NPTS * 192 * 4);
    float* P    = (float*)carve((size_t)NPTS * 512 * 4);
    float* V1   = (float*)carve((size_t)NPTS * 384 * 4);
    float* O0   = (float*)carve((size_t)NPTS * 128 * 4);
    float* O1   = (float*)carve((size_t)NPTS * 384 * 4);
    float* Hb   = P;   // alias: FFN hidden (10.24M floats) over dead P+V1+O0
    float* gt   = O1;  // alias: gate over dead O1

    // kNN + geometry precompute
    knn_k<<<625, 64, 0, stream>>>(coors, idxp, rbfp, rup);

    // f0 = feats @ Wemb
    { BP4 bp{{Wemb}};
      gemm_k<0,false,false,false,false><<<dim3(4,79),256,0,stream>>>(bp,256,nullptr,nullptr,feats,256,f0,256,NPTS,256); }
    hipMemsetAsync(f1, 0, (size_t)NPTS * 192 * 4, stream);

    for (int l = 0; l < 4; ++l) {
        ln_k<<<2500,256,0,stream>>>(f0, f0n, NPTS);
        // P = f0n @ [Wq|Wk|Wv0|Wvr]
        { BP4 bp{{Wq + l*32768, Wk + l*32768, Wv0 + l*32768, Wvr + l*32768}};
          gemm_k<0,false,false,false,true><<<dim3(8,79),256,0,stream>>>(bp,128,nullptr,nullptr,f0n,256,P,512,NPTS,256); }
        // V1 = f1 @ Wv1  (rows n*3+v)
        { BP4 bp{{Wv1 + l*8192}};
          gemm_k<0,false,false,false,false><<<dim3(2,235),256,0,stream>>>(bp,128,nullptr,nullptr,f1,64,V1,128,NPTS*3,64); }
        attn_k<<<NPTS,128,0,stream>>>(P, V1, rbfp, rup, idxp, We + l*2048, Wer + l*2048, O0, O1);
        // f0 += O0 @ Wo0
        { BP4 bp{{Wo0 + l*32768}};
          gemm_k<0,true,false,false,false><<<dim3(4,79),256,0,stream>>>(bp,256,nullptr,nullptr,O0,128,f0,256,NPTS,128); }
        // f1 += O1 @ Wo1
        { BP4 bp{{Wo1 + l*8192}};
          gemm_k<0,true,false,false,false><<<dim3(1,235),256,0,stream>>>(bp,64,nullptr,nullptr,O1,128,f1,64,NPTS*3,128); }
        ln_k<<<2500,256,0,stream>>>(f0, f0n, NPTS);
        // Hb = gelu(f0n @ Wf1 + bf1)
        { BP4 bp{{Wf1 + l*262144}};
          gemm_k<1,false,true,false,false><<<dim3(16,79),256,0,stream>>>(bp,1024,bf1 + l*1024,nullptr,f0n,256,Hb,1024,NPTS,256); }
        // f0 += Hb @ Wf2 + bf2
        { BP4 bp{{Wf2 + l*262144}};
          gemm_k<0,true,true,false,false><<<dim3(4,79),256,0,stream>>>(bp,256,bf2 + l*256,nullptr,Hb,1024,f0,256,NPTS,1024); }
        // gate = sigmoid(f0n @ Wg)
        { BP4 bp{{Wg + l*16384}};
          gemm_k<2,false,false,false,false><<<dim3(1,79),256,0,stream>>>(bp,64,nullptr,nullptr,f0n,256,gt,64,NPTS,256); }
        // f1 += (f1 @ Wvff) * gate[n]
        { BP4 bp{{Wvff + l*4096}};
          gemm_k<0,true,false,true,false><<<dim3(1,235),256,0,stream>>>(bp,64,nullptr,gt,f1,64,f1,64,NPTS*3,64); }
    }

    // pred_scalar = f0 @ Ws + bs
    { BP4 bp{{Ws}};
      gemm_k<0,false,true,false,false><<<dim3(4,79),256,0,stream>>>(bp,256,bs,nullptr,f0,256,out,256,NPTS,256); }
    // pred_vector
    vecout_k<<<118,256,0,stream>>>(f1, wv, out + (size_t)NPTS * 256);
}

// Round 2
// 1596.144 us; speedup vs baseline: 1.8806x; 1.8806x over previous
//
#include <hip/hip_runtime.h>
#include <math.h>

// ---------------------------------------------------------------------------
// EquiformerPointHead — round 2: fp16-MFMA GEMMs + parallelized kNN.
// N=10000, C0=256, C1=64, DEPTH=4, HEADS=4, DH=32, H=128, K=16, R=16
// ---------------------------------------------------------------------------

#define NPTS 10000

using f16x8 = __attribute__((ext_vector_type(8))) _Float16;
using f16x4 = __attribute__((ext_vector_type(4))) _Float16;
using f32x4 = __attribute__((ext_vector_type(4))) float;

__device__ __forceinline__ float gelu_f(float x) {
    float u = 0.7978845608028654f * (x + 0.044715f * x * x * x);
    return 0.5f * x * (1.0f + tanhf(u));
}
__device__ __forceinline__ float sigmoid_f(float x) {
    return 1.0f / (1.0f + expf(-x));
}
__device__ __forceinline__ f16x8 zero8() {
    f16x8 v;
    #pragma unroll
    for (int i = 0; i < 8; ++i) v[i] = (_Float16)0.f;
    return v;
}

// ---------------------------------------------------------------------------
// fp16 MFMA GEMM: C[MxN] = epi(A[MxK] @ Bt[NxK]^T), fp32 accumulate.
// BM=64, BN=128, BK=32, 256 threads = 4 waves (2x2), wave tile 32x64.
// ACT: 0 none, 1 gelu, 2 sigmoid. ADD: +=C. BIAS: +bias[col].
// GATED: *gate[(row/3)*64+col]. OUT16: 0 f32 only, 1 f16 only, 2 both.
// LDS 16B-slot swizzle: slot = s ^ ((row>>1)&3)  (balanced banks both ways).
// ---------------------------------------------------------------------------
template<int ACT, bool ADD, bool BIAS, bool GATED, int OUT16>
__global__ __launch_bounds__(256)
void hgemm_k(const _Float16* __restrict__ A, int lda,
             const _Float16* __restrict__ Bt,
             const float* __restrict__ bias,
             const float* __restrict__ gate,
             float* __restrict__ C, _Float16* __restrict__ Ch, int ldc,
             int M, int N, int K)
{
    __shared__ _Float16 As[64 * 32];
    __shared__ _Float16 Bs[128 * 32];
    const int bm = blockIdx.y * 64;
    const int bn = blockIdx.x * 128;
    const int tid = threadIdx.x;
    const int lane = tid & 63;
    const int wid = tid >> 6;
    const int wr = wid >> 1, wc = wid & 1;
    const int l15 = lane & 15, lg = lane >> 4;

    f32x4 acc[2][4];
    #pragma unroll
    for (int mi = 0; mi < 2; ++mi)
        #pragma unroll
        for (int ni = 0; ni < 4; ++ni)
            #pragma unroll
            for (int r = 0; r < 4; ++r) acc[mi][ni][r] = 0.f;

    for (int kt = 0; kt < K; kt += 32) {
        {   // stage A: 64 rows x 4 slots, one 16B chunk per thread
            int row = tid >> 2, s = tid & 3;
            f16x8 v = zero8();
            if (bm + row < M) v = *(const f16x8*)(A + (size_t)(bm + row) * lda + kt + s * 8);
            ((f16x8*)As)[row * 4 + (s ^ ((row >> 1) & 3))] = v;
        }
        #pragma unroll
        for (int i = 0; i < 2; ++i) {  // stage B: 128 rows x 4 slots
            int c = tid + i * 256;
            int row = c >> 2, s = c & 3;
            f16x8 v = zero8();
            if (bn + row < N) v = *(const f16x8*)(Bt + (size_t)(bn + row) * K + kt + s * 8);
            ((f16x8*)Bs)[row * 4 + (s ^ ((row >> 1) & 3))] = v;
        }
        __syncthreads();
        f16x8 af[2], bf[4];
        #pragma unroll
        for (int mi = 0; mi < 2; ++mi) {
            int row = wr * 32 + mi * 16 + l15;
            af[mi] = ((const f16x8*)As)[row * 4 + (lg ^ ((row >> 1) & 3))];
        }
        #pragma unroll
        for (int ni = 0; ni < 4; ++ni) {
            int row = wc * 64 + ni * 16 + l15;
            bf[ni] = ((const f16x8*)Bs)[row * 4 + (lg ^ ((row >> 1) & 3))];
        }
        #pragma unroll
        for (int mi = 0; mi < 2; ++mi)
            #pragma unroll
            for (int ni = 0; ni < 4; ++ni)
                acc[mi][ni] = __builtin_amdgcn_mfma_f32_16x16x32_f16(af[mi], bf[ni], acc[mi][ni], 0, 0, 0);
        __syncthreads();
    }

    // epilogue: C/D layout col=lane&15, row=(lane>>4)*4+reg
    #pragma unroll
    for (int mi = 0; mi < 2; ++mi) {
        #pragma unroll
        for (int ni = 0; ni < 4; ++ni) {
            int col = bn + wc * 64 + ni * 16 + l15;
            #pragma unroll
            for (int r = 0; r < 4; ++r) {
                int row = bm + wr * 32 + mi * 16 + lg * 4 + r;
                if (row < M && col < N) {
                    float v = acc[mi][ni][r];
                    if (BIAS) v += bias[col];
                    if (ACT == 1) v = gelu_f(v);
                    if (ACT == 2) v = sigmoid_f(v);
                    if (GATED) v *= gate[(size_t)(row / 3) * 64 + col];
                    size_t o = (size_t)row * ldc + col;
                    if (ADD) v += C[o];
                    if (OUT16 != 1) C[o] = v;
                    if (OUT16 >= 1) Ch[o] = (_Float16)v;
                }
            }
        }
    }
}

// ---------------------------------------------------------------------------
// Batched weight transpose-convert: src fp32 [K][N] -> dst f16 [N][K].
// 46 descriptors in kernel args; 32x32 LDS tile transpose per block.
// ---------------------------------------------------------------------------
struct TXT { const float* src; _Float16* dst; int K, N, blk0; };
struct TXA { TXT t[46]; };

__global__ __launch_bounds__(256)
void tconv_k(TXA g)
{
    __shared__ float tile[32][33];
    int b = blockIdx.x;
    int d = 0;
    while (d < 45 && b >= g.t[d + 1].blk0) ++d;
    int local = b - g.t[d].blk0;
    const float* src = g.t[d].src;
    _Float16* dst = g.t[d].dst;
    int K = g.t[d].K, N = g.t[d].N;
    int ntj = N >> 5;
    int ti = local / ntj;
    int tj = local - ti * ntj;
    int tx = threadIdx.x & 31, ty = threadIdx.x >> 5;
    #pragma unroll
    for (int i = 0; i < 4; ++i)
        tile[ty + i * 8][tx] = src[(size_t)(ti * 32 + ty + i * 8) * N + tj * 32 + tx];
    __syncthreads();
    #pragma unroll
    for (int i = 0; i < 4; ++i)
        dst[(size_t)(tj * 32 + ty + i * 8) * K + ti * 32 + tx] = (_Float16)tile[tx][ty + i * 8];
}

// fp32 -> f16 elementwise (8 per thread)
__global__ __launch_bounds__(256)
void cvt_k(const float* __restrict__ src, _Float16* __restrict__ dst, int n8)
{
    int i = blockIdx.x * 256 + threadIdx.x;
    if (i >= n8) return;
    float4 a = ((const float4*)src)[2 * i];
    float4 b = ((const float4*)src)[2 * i + 1];
    f16x8 o = {(_Float16)a.x, (_Float16)a.y, (_Float16)a.z, (_Float16)a.w,
               (_Float16)b.x, (_Float16)b.y, (_Float16)b.z, (_Float16)b.w};
    ((f16x8*)dst)[i] = o;
}

// ---------------------------------------------------------------------------
// LayerNorm over rows of 256, f16 output. One wave per row, 4 rows/block.
// ---------------------------------------------------------------------------
__global__ __launch_bounds__(256)
void ln_k(const float* __restrict__ x, _Float16* __restrict__ y, int M)
{
    int lane = threadIdx.x & 63;
    int row = blockIdx.x * 4 + (threadIdx.x >> 6);
    if (row >= M) return;
    float4 v = ((const float4*)(x + (size_t)row * 256))[lane];
    float s = v.x + v.y + v.z + v.w;
    #pragma unroll
    for (int m = 32; m >= 1; m >>= 1) s += __shfl_xor(s, m);
    float mean = s * 0.00390625f;
    float dx = v.x - mean, dy = v.y - mean, dz = v.z - mean, dw = v.w - mean;
    float vs = dx * dx + dy * dy + dz * dz + dw * dw;
    #pragma unroll
    for (int m = 32; m >= 1; m >>= 1) vs += __shfl_xor(vs, m);
    float rs = rsqrtf(vs * 0.00390625f + 1e-6f);
    f16x4 o = {(_Float16)(dx * rs), (_Float16)(dy * rs), (_Float16)(dz * rs), (_Float16)(dw * rs)};
    ((f16x4*)(y + (size_t)row * 256))[lane] = o;
}

// ---------------------------------------------------------------------------
// kNN: 16 queries x 16 candidate-parts per 256-thread block. Exact (q-c)^2
// in reference order (contract off) to match numpy top-k boundaries.
// ---------------------------------------------------------------------------
#define KNN_CHUNK 1024
__global__ __launch_bounds__(256)
void knn_k(const float* __restrict__ coors, int* __restrict__ idxp,
           float* __restrict__ rbfp, float* __restrict__ rup)
{
    #pragma clang fp contract(off)
    __shared__ float cf[KNN_CHUNK * 3];
    __shared__ float mD[16][16][16];
    __shared__ int   mI[16][16][16];
    __shared__ int   cu[16][16];
    const int t = threadIdx.x;
    const int qq = t & 15;
    const int part = t >> 4;
    const int n = blockIdx.x * 16 + qq;
    const float qx = coors[n * 3 + 0], qy = coors[n * 3 + 1], qz = coors[n * 3 + 2];

    float bd[16]; int bi[16];
    #pragma unroll
    for (int m = 0; m < 16; ++m) { bd[m] = 3.4e38f; bi[m] = 0; }

    for (int cbase = 0; cbase < NPTS; cbase += KNN_CHUNK) {
        int cn = min(KNN_CHUNK, NPTS - cbase);
        __syncthreads();
        for (int qi = t; qi < cn * 3; qi += 256) cf[qi] = coors[cbase * 3 + qi];
        __syncthreads();
        int nj = cn >> 4;  // cn divisible by 16 (1024, 784)
        for (int jj = 0; jj < nj; ++jj) {
            int local = jj * 16 + part;
            float dx = cf[local * 3 + 0] - qx;
            float dy = cf[local * 3 + 1] - qy;
            float dz = cf[local * 3 + 2] - qz;
            float d2 = dx * dx + dy * dy;
            d2 = d2 + dz * dz;
            if (d2 < bd[15]) {
                int j = cbase + local;
                #pragma unroll
                for (int m = 15; m >= 1; --m) {
                    bool up = bd[m - 1] > d2;
                    float nd = up ? bd[m - 1] : (bd[m] > d2 ? d2 : bd[m]);
                    int   ni = up ? bi[m - 1] : (bd[m] > d2 ? j : bi[m]);
                    bd[m] = nd; bi[m] = ni;
                }
                if (bd[0] > d2) { bd[0] = d2; bi[0] = j; }
            }
        }
    }
    __syncthreads();
    #pragma unroll
    for (int m = 0; m < 16; ++m) { mD[qq][part][m] = bd[m]; mI[qq][part][m] = bi[m]; }
    __syncthreads();

    if (t < 16) {
        const int nn = blockIdx.x * 16 + t;
        #pragma unroll
        for (int p = 0; p < 16; ++p) cu[t][p] = 0;
        for (int m = 0; m < 16; ++m) {
            float best = 3.5e38f; int wp = 0;
            #pragma unroll
            for (int p = 0; p < 16; ++p) {
                float v = mD[t][p][cu[t][p]];
                if (v < best) { best = v; wp = p; }
            }
            int j = mI[t][wp][cu[t][wp]];
            cu[t][wp]++;
            idxp[nn * 16 + m] = j;
            float dist = sqrtf(best + 1e-6f);
            float rx = coors[j * 3 + 0] - qx;
            float ry = coors[j * 3 + 1] - qy;
            float rz = coors[j * 3 + 2] - qz;
            rup[(nn * 16 + m) * 3 + 0] = rx / dist;
            rup[(nn * 16 + m) * 3 + 1] = ry / dist;
            rup[(nn * 16 + m) * 3 + 2] = rz / dist;
            #pragma unroll
            for (int r = 0; r < 16; ++r) {
                float c = (4.0f / 15.0f) * r;
                float dd = dist - c;
                rbfp[(size_t)nn * 256 + m * 16 + r] = expf(-dd * dd * 8.0f);
            }
        }
    }
}

// ---------------------------------------------------------------------------
// Fused attention: one block per node, 128 threads. fp32 math, f16 outputs.
// P per node: [q(128) | k(128) | v0(128) | vr(128)] fp32.
// V1 per node: [v=0 (128) | v=1 | v=2] fp32. O0/O1 f16.
// ---------------------------------------------------------------------------
__global__ __launch_bounds__(128)
void attn_k(const float* __restrict__ P, const float* __restrict__ V1,
            const float* __restrict__ rbf, const float* __restrict__ ru,
            const int* __restrict__ idx,
            const float* __restrict__ We, const float* __restrict__ Wer,
            _Float16* __restrict__ O0, _Float16* __restrict__ O1)
{
    const int n = blockIdx.x;
    const int hd = threadIdx.x;
    const int h = hd >> 5;
    __shared__ float WeS[16][128], WerS[16][128];
    __shared__ float rbfS[16][16];
    __shared__ float ruS[16][4];
    __shared__ int   idxS[16];
    __shared__ float logitsS[4][16];
    __shared__ float attnS[4][16];

    #pragma unroll
    for (int r = 0; r < 16; ++r) {
        WeS[r][hd]  = We[r * 128 + hd];
        WerS[r][hd] = Wer[r * 128 + hd];
    }
    ((float*)rbfS)[hd]       = rbf[(size_t)n * 256 + hd];
    ((float*)rbfS)[hd + 128] = rbf[(size_t)n * 256 + 128 + hd];
    if (hd < 16) idxS[hd] = idx[n * 16 + hd];
    if (hd < 48) ruS[hd / 3][hd % 3] = ru[n * 48 + hd];
    float q = P[(size_t)n * 512 + hd];
    __syncthreads();

    #pragma unroll 4
    for (int k = 0; k < 16; ++k) {
        int j = idxS[k];
        float kv = P[(size_t)j * 512 + 128 + hd];
        float racc = 0.f;
        #pragma unroll
        for (int r = 0; r < 16; ++r) racc += rbfS[k][r] * WeS[r][hd];
        kv += racc;
        float prod = q * kv;
        prod += __shfl_xor(prod, 1);
        prod += __shfl_xor(prod, 2);
        prod += __shfl_xor(prod, 4);
        prod += __shfl_xor(prod, 8);
        prod += __shfl_xor(prod, 16);
        if ((hd & 31) == 0) logitsS[h][k] = prod * 0.17677669529663687f;
    }
    __syncthreads();

    {
        float mx = -1e30f;
        #pragma unroll
        for (int k = 0; k < 16; ++k) mx = fmaxf(mx, logitsS[h][k]);
        float aw[16]; float s = 0.f;
        #pragma unroll
        for (int k = 0; k < 16; ++k) { aw[k] = expf(logitsS[h][k] - mx); s += aw[k]; }
        float inv = 1.f / s;
        if ((hd & 31) == 0) {
            #pragma unroll
            for (int k = 0; k < 16; ++k) attnS[h][k] = aw[k] * inv;
        }
    }
    __syncthreads();

    float o0 = 0.f, o1x = 0.f, o1y = 0.f, o1z = 0.f;
    #pragma unroll 4
    for (int k = 0; k < 16; ++k) {
        int j = idxS[k];
        float a = attnS[h][k];
        const float* pj = P + (size_t)j * 512;
        float v0 = pj[256 + hd];
        float ge = pj[384 + hd];
        float racc = 0.f;
        #pragma unroll
        for (int r = 0; r < 16; ++r) racc += rbfS[k][r] * WerS[r][hd];
        ge += racc;
        const float* vj = V1 + (size_t)j * 384;
        o0  += a * v0;
        o1x += a * (vj[hd]       + ge * ruS[k][0]);
        o1y += a * (vj[128 + hd] + ge * ruS[k][1]);
        o1z += a * (vj[256 + hd] + ge * ruS[k][2]);
    }
    O0[(size_t)n * 128 + hd] = (_Float16)o0;
    _Float16* o1p = O1 + (size_t)n * 384;
    o1p[hd] = (_Float16)o1x; o1p[128 + hd] = (_Float16)o1y; o1p[256 + hd] = (_Float16)o1z;
}

// ---------------------------------------------------------------------------
__global__ __launch_bounds__(256)
void vecout_k(const float* __restrict__ f1, const float* __restrict__ wv,
              float* __restrict__ out2)
{
    int row = blockIdx.x * 256 + threadIdx.x;
    if (row >= NPTS * 3) return;
    const float4* fr = (const float4*)(f1 + (size_t)row * 64);
    const float4* w4 = (const float4*)wv;
    float s = 0.f;
    #pragma unroll
    for (int c = 0; c < 16; ++c) {
        float4 a = fr[c], b = w4[c];
        s += a.x * b.x + a.y * b.y + a.z * b.z + a.w * b.w;
    }
    out2[row] = s;
}

// ---------------------------------------------------------------------------
extern "C" void kernel_launch(void* const* d_in, const int* in_sizes, int n_in,
                              void* d_out, int out_size, void* d_ws, size_t ws_size,
                              hipStream_t stream)
{
    (void)in_sizes; (void)n_in; (void)out_size; (void)ws_size;
    const float* feats = (const float*)d_in[0];
    const float* coors = (const float*)d_in[1];
    const float* Wemb = (const float*)d_in[3];
    const float* Wq   = (const float*)d_in[4];
    const float* Wk   = (const float*)d_in[5];
    const float* Wv0  = (const float*)d_in[6];
    const float* Wvr  = (const float*)d_in[7];
    const float* We   = (const float*)d_in[8];
    const float* Wer  = (const float*)d_in[9];
    const float* Wv1  = (const float*)d_in[10];
    const float* Wo0  = (const float*)d_in[11];
    const float* Wo1  = (const float*)d_in[12];
    const float* Wf1  = (const float*)d_in[13];
    const float* bf1  = (const float*)d_in[14];
    const float* Wf2  = (const float*)d_in[15];
    const float* bf2  = (const float*)d_in[16];
    const float* Wg   = (const float*)d_in[17];
    const float* Wvff = (const float*)d_in[18];
    const float* Ws   = (const float*)d_in[19];
    const float* bs   = (const float*)d_in[20];
    const float* wv   = (const float*)d_in[21];
    float* out = (float*)d_out;

    char* ws = (char*)d_ws;
    size_t off = 0;
    auto carve = [&](size_t bytes) -> char* {
        char* p = ws + off;
        off += (bytes + 255) & ~(size_t)255;
        return p;
    };
    int*      idxp   = (int*)      carve((size_t)NPTS * 16 * 4);
    float*    rbfp   = (float*)    carve((size_t)NPTS * 256 * 4);
    float*    rup    = (float*)    carve((size_t)NPTS * 48 * 4);
    float*    f0     = (float*)    carve((size_t)NPTS * 256 * 4);
    float*    f1     = (float*)    carve((size_t)NPTS * 192 * 4);
    float*    P      = (float*)    carve((size_t)NPTS * 512 * 4);   // Hb_h aliases
    float*    V1     = (float*)    carve((size_t)NPTS * 384 * 4);
    float*    gt     = (float*)    carve((size_t)NPTS * 64 * 4);
    _Float16* f0n_h  = (_Float16*) carve((size_t)NPTS * 256 * 2);
    _Float16* f0h    = (_Float16*) carve((size_t)NPTS * 256 * 2);
    _Float16* f1h    = (_Float16*) carve((size_t)NPTS * 192 * 2);
    _Float16* O0h    = (_Float16*) carve((size_t)NPTS * 128 * 2);
    _Float16* O1h    = (_Float16*) carve((size_t)NPTS * 384 * 2);
    _Float16* featsh = (_Float16*) carve((size_t)NPTS * 256 * 2);
    _Float16* WembT  = (_Float16*) carve(65536 * 2);
    _Float16* WqkvrT = (_Float16*) carve(4 * 131072 * 2);
    _Float16* Wv1T   = (_Float16*) carve(4 * 8192 * 2);
    _Float16* Wo0T   = (_Float16*) carve(4 * 32768 * 2);
    _Float16* Wo1T   = (_Float16*) carve(4 * 8192 * 2);
    _Float16* Wf1T   = (_Float16*) carve(4 * 262144 * 2);
    _Float16* Wf2T   = (_Float16*) carve(4 * 262144 * 2);
    _Float16* WgT    = (_Float16*) carve(4 * 16384 * 2);
    _Float16* WvffT  = (_Float16*) carve(4 * 4096 * 2);
    _Float16* WsT    = (_Float16*) carve(65536 * 2);
    _Float16* Hbh    = (_Float16*) P;  // alias: 10000x1024 f16 = 20.48MB over P

    // ---- weight transpose-convert (46 descriptors, one launch) ----
    TXA ta;
    int blk = 0, di = 0;
    auto addt = [&](const float* s, _Float16* d, int Ks, int Ns) {
        ta.t[di].src = s; ta.t[di].dst = d; ta.t[di].K = Ks; ta.t[di].N = Ns;
        ta.t[di].blk0 = blk; blk += (Ks / 32) * (Ns / 32); ++di;
    };
    addt(Wemb, WembT, 256, 256);
    for (int l = 0; l < 4; ++l) {
        addt(Wq  + l * 32768, WqkvrT + (size_t)l * 131072 +     0, 256, 128);
        addt(Wk  + l * 32768, WqkvrT + (size_t)l * 131072 + 32768, 256, 128);
        addt(Wv0 + l * 32768, WqkvrT + (size_t)l * 131072 + 65536, 256, 128);
        addt(Wvr + l * 32768, WqkvrT + (size_t)l * 131072 + 98304, 256, 128);
    }
    for (int l = 0; l < 4; ++l) addt(Wv1  + l * 8192,   Wv1T  + l * 8192,   64, 128);
    for (int l = 0; l < 4; ++l) addt(Wo0  + l * 32768,  Wo0T  + l * 32768,  128, 256);
    for (int l = 0; l < 4; ++l) addt(Wo1  + l * 8192,   Wo1T  + l * 8192,   128, 64);
    for (int l = 0; l < 4; ++l) addt(Wf1  + l * 262144, Wf1T  + l * 262144, 256, 1024);
    for (int l = 0; l < 4; ++l) addt(Wf2  + l * 262144, Wf2T  + l * 262144, 1024, 256);
    for (int l = 0; l < 4; ++l) addt(Wg   + l * 16384,  WgT   + l * 16384,  256, 64);
    for (int l = 0; l < 4; ++l) addt(Wvff + l * 4096,   WvffT + l * 4096,   64, 64);
    addt(Ws, WsT, 256, 256);
    tconv_k<<<blk, 256, 0, stream>>>(ta);

    cvt_k<<<(NPTS * 256 / 8 + 255) / 256, 256, 0, stream>>>(feats, featsh, NPTS * 256 / 8);
    knn_k<<<625, 256, 0, stream>>>(coors, idxp, rbfp, rup);

    // f0 = feats @ Wemb
    hgemm_k<0,false,false,false,0><<<dim3(2,157),256,0,stream>>>(featsh,256,WembT,nullptr,nullptr,f0,nullptr,256,NPTS,256,256);
    hipMemsetAsync(f1, 0, (size_t)NPTS * 192 * 4, stream);
    hipMemsetAsync(f1h, 0, (size_t)NPTS * 192 * 2, stream);

    for (int l = 0; l < 4; ++l) {
        ln_k<<<2500,256,0,stream>>>(f0, f0n_h, NPTS);
        // P = f0n @ [Wq|Wk|Wv0|Wvr]
        hgemm_k<0,false,false,false,0><<<dim3(4,157),256,0,stream>>>(f0n_h,256,WqkvrT+(size_t)l*131072,nullptr,nullptr,P,nullptr,512,NPTS,512,256);
        // V1 = f1 @ Wv1
        hgemm_k<0,false,false,false,0><<<dim3(1,469),256,0,stream>>>(f1h,64,Wv1T+l*8192,nullptr,nullptr,V1,nullptr,128,NPTS*3,128,64);
        attn_k<<<NPTS,128,0,stream>>>(P, V1, rbfp, rup, idxp, We + l*2048, Wer + l*2048, O0h, O1h);
        // f0 += O0 @ Wo0
        hgemm_k<0,true,false,false,0><<<dim3(2,157),256,0,stream>>>(O0h,128,Wo0T+l*32768,nullptr,nullptr,f0,nullptr,256,NPTS,256,128);
        // f1 += O1 @ Wo1  (+ f16 mirror)
        hgemm_k<0,true,false,false,2><<<dim3(1,469),256,0,stream>>>(O1h,128,Wo1T+l*8192,nullptr,nullptr,f1,f1h,64,NPTS*3,64,128);
        ln_k<<<2500,256,0,stream>>>(f0, f0n_h, NPTS);
        // Hb = gelu(f0n @ Wf1 + bf1)  (f16 only)
        hgemm_k<1,false,true,false,1><<<dim3(8,157),256,0,stream>>>(f0n_h,256,Wf1T+(size_t)l*262144,bf1+l*1024,nullptr,nullptr,Hbh,1024,NPTS,1024,256);
        // f0 += Hb @ Wf2 + bf2  (+ f16 mirror f0h)
        hgemm_k<0,true,true,false,2><<<dim3(2,157),256,0,stream>>>(Hbh,1024,Wf2T+(size_t)l*262144,bf2+l*256,nullptr,f0,f0h,256,NPTS,256,1024);
        // gate = sigmoid(f0n @ Wg)
        hgemm_k<2,false,false,false,0><<<dim3(1,157),256,0,stream>>>(f0n_h,256,WgT+l*16384,nullptr,nullptr,gt,nullptr,64,NPTS,64,256);
        // f1 += (f1 @ Wvff) * gate  (+ f16 mirror)
        hgemm_k<0,true,false,true,2><<<dim3(1,469),256,0,stream>>>(f1h,64,WvffT+l*4096,nullptr,gt,f1,f1h,64,NPTS*3,64,64);
    }

    // pred_scalar = f0 @ Ws + bs
    hgemm_k<0,false,true,false,0><<<dim3(2,157),256,0,stream>>>(f0h,256,WsT,bs,nullptr,out,nullptr,256,NPTS,256,256);
    // pred_vector
    vecout_k<<<118,256,0,stream>>>(f1, wv, out + (size_t)NPTS * 256);
}

// Round 3
// 1263.332 us; speedup vs baseline: 2.3760x; 1.2634x over previous
//
#include <hip/hip_runtime.h>
#include <math.h>

// ---------------------------------------------------------------------------
// EquiformerPointHead — round 3: branchless 2-pass kNN, f16 P/V1, BN-templated
// MFMA GEMM with fused Wf1+Wg epilogue.
// N=10000, C0=256, C1=64, DEPTH=4, HEADS=4, DH=32, H=128, K=16, R=16
// ---------------------------------------------------------------------------

#define NPTS 10000

using f16x8 = __attribute__((ext_vector_type(8))) _Float16;
using f16x4 = __attribute__((ext_vector_type(4))) _Float16;
using f32x4 = __attribute__((ext_vector_type(4))) float;

__device__ __forceinline__ float gelu_f(float x) {
    float u = 0.7978845608028654f * (x + 0.044715f * x * x * x);
    return 0.5f * x * (1.0f + tanhf(u));
}
__device__ __forceinline__ float sigmoid_f(float x) {
    return 1.0f / (1.0f + expf(-x));
}
__device__ __forceinline__ f16x8 zero8() {
    f16x8 v;
    #pragma unroll
    for (int i = 0; i < 8; ++i) v[i] = (_Float16)0.f;
    return v;
}

// ---------------------------------------------------------------------------
// fp16 MFMA GEMM: C[MxN] = epi(A[MxK] @ Bt[NxK]^T), fp32 accumulate.
// BM=64, BN in {64,128}, BK=32, 256 threads = 4 waves (2x2).
// ACT: 0 none, 1 gelu, 2 sigmoid, 3 split(col<1024: gelu->Ch f16,
//      else sigmoid->gout f32 [row*64+col-1024]).
// ADD: +=C. BIAS: +bias[col] (ACT3: only col<1024). GATED: *gate[(row/3)*64+col].
// OUT16: 0 f32 only, 1 f16 only, 2 both.
// LDS 16B-slot swizzle: slot = s ^ ((row>>1)&3).
// ---------------------------------------------------------------------------
template<int ACT, bool ADD, bool BIAS, bool GATED, int OUT16, int BN>
__global__ __launch_bounds__(256)
void hgemm_k(const _Float16* __restrict__ A, int lda,
             const _Float16* __restrict__ Bt,
             const float* __restrict__ bias,
             const float* __restrict__ gate,
             float* __restrict__ gout,
             float* __restrict__ C, _Float16* __restrict__ Ch, int ldc,
             int M, int N, int K)
{
    constexpr int NI = BN / 32;           // n-tiles per wave
    __shared__ _Float16 As[64 * 32];
    __shared__ _Float16 Bs[BN * 32];
    const int bm = blockIdx.y * 64;
    const int bn = blockIdx.x * BN;
    const int tid = threadIdx.x;
    const int lane = tid & 63;
    const int wid = tid >> 6;
    const int wr = wid >> 1, wc = wid & 1;
    const int l15 = lane & 15, lg = lane >> 4;

    f32x4 acc[2][NI];
    #pragma unroll
    for (int mi = 0; mi < 2; ++mi)
        #pragma unroll
        for (int ni = 0; ni < NI; ++ni)
            #pragma unroll
            for (int r = 0; r < 4; ++r) acc[mi][ni][r] = 0.f;

    for (int kt = 0; kt < K; kt += 32) {
        {   // stage A: 64 rows x 4 slots
            int row = tid >> 2, s = tid & 3;
            f16x8 v = zero8();
            if (bm + row < M) v = *(const f16x8*)(A + (size_t)(bm + row) * lda + kt + s * 8);
            ((f16x8*)As)[row * 4 + (s ^ ((row >> 1) & 3))] = v;
        }
        #pragma unroll
        for (int i = 0; i < BN / 64; ++i) {  // stage B: BN rows x 4 slots
            int c = tid + i * 256;
            int row = c >> 2, s = c & 3;
            f16x8 v = zero8();
            if (bn + row < N) v = *(const f16x8*)(Bt + (size_t)(bn + row) * K + kt + s * 8);
            ((f16x8*)Bs)[row * 4 + (s ^ ((row >> 1) & 3))] = v;
        }
        __syncthreads();
        f16x8 af[2], bf[NI];
        #pragma unroll
        for (int mi = 0; mi < 2; ++mi) {
            int row = wr * 32 + mi * 16 + l15;
            af[mi] = ((const f16x8*)As)[row * 4 + (lg ^ ((row >> 1) & 3))];
        }
        #pragma unroll
        for (int ni = 0; ni < NI; ++ni) {
            int row = wc * (BN / 2) + ni * 16 + l15;
            bf[ni] = ((const f16x8*)Bs)[row * 4 + (lg ^ ((row >> 1) & 3))];
        }
        #pragma unroll
        for (int mi = 0; mi < 2; ++mi)
            #pragma unroll
            for (int ni = 0; ni < NI; ++ni)
                acc[mi][ni] = __builtin_amdgcn_mfma_f32_16x16x32_f16(af[mi], bf[ni], acc[mi][ni], 0, 0, 0);
        __syncthreads();
    }

    // epilogue: C/D layout col=lane&15, row=(lane>>4)*4+reg
    #pragma unroll
    for (int mi = 0; mi < 2; ++mi) {
        #pragma unroll
        for (int ni = 0; ni < NI; ++ni) {
            int col = bn + wc * (BN / 2) + ni * 16 + l15;
            #pragma unroll
            for (int r = 0; r < 4; ++r) {
                int row = bm + wr * 32 + mi * 16 + lg * 4 + r;
                if (row < M && col < N) {
                    float v = acc[mi][ni][r];
                    if (ACT == 3) {
                        if (col < 1024) {
                            if (BIAS) v += bias[col];
                            v = gelu_f(v);
                            Ch[(size_t)row * ldc + col] = (_Float16)v;
                        } else {
                            gout[(size_t)row * 64 + (col - 1024)] = sigmoid_f(v);
                        }
                    } else {
                        if (BIAS) v += bias[col];
                        if (ACT == 1) v = gelu_f(v);
                        if (ACT == 2) v = sigmoid_f(v);
                        if (GATED) v *= gate[(size_t)(row / 3) * 64 + col];
                        size_t o = (size_t)row * ldc + col;
                        if (ADD) v += C[o];
                        if (OUT16 != 1) C[o] = v;
                        if (OUT16 >= 1) Ch[o] = (_Float16)v;
                    }
                }
            }
        }
    }
}

// ---------------------------------------------------------------------------
// Batched weight transpose-convert: src fp32 [K][N] -> dst f16 [N][K].
// ---------------------------------------------------------------------------
struct TXT { const float* src; _Float16* dst; int K, N, blk0; };
struct TXA { TXT t[46]; };

__global__ __launch_bounds__(256)
void tconv_k(TXA g)
{
    __shared__ float tile[32][33];
    int b = blockIdx.x;
    int d = 0;
    while (d < 45 && b >= g.t[d + 1].blk0) ++d;
    int local = b - g.t[d].blk0;
    const float* src = g.t[d].src;
    _Float16* dst = g.t[d].dst;
    int K = g.t[d].K, N = g.t[d].N;
    int ntj = N >> 5;
    int ti = local / ntj;
    int tj = local - ti * ntj;
    int tx = threadIdx.x & 31, ty = threadIdx.x >> 5;
    #pragma unroll
    for (int i = 0; i < 4; ++i)
        tile[ty + i * 8][tx] = src[(size_t)(ti * 32 + ty + i * 8) * N + tj * 32 + tx];
    __syncthreads();
    #pragma unroll
    for (int i = 0; i < 4; ++i)
        dst[(size_t)(tj * 32 + ty + i * 8) * K + ti * 32 + tx] = (_Float16)tile[tx][ty + i * 8];
}

// fp32 -> f16 elementwise (8 per thread)
__global__ __launch_bounds__(256)
void cvt_k(const float* __restrict__ src, _Float16* __restrict__ dst, int n8)
{
    int i = blockIdx.x * 256 + threadIdx.x;
    if (i >= n8) return;
    float4 a = ((const float4*)src)[2 * i];
    float4 b = ((const float4*)src)[2 * i + 1];
    f16x8 o = {(_Float16)a.x, (_Float16)a.y, (_Float16)a.z, (_Float16)a.w,
               (_Float16)b.x, (_Float16)b.y, (_Float16)b.z, (_Float16)b.w};
    ((f16x8*)dst)[i] = o;
}

// ---------------------------------------------------------------------------
// LayerNorm over rows of 256, f16 output.
// ---------------------------------------------------------------------------
__global__ __launch_bounds__(256)
void ln_k(const float* __restrict__ x, _Float16* __restrict__ y, int M)
{
    int lane = threadIdx.x & 63;
    int row = blockIdx.x * 4 + (threadIdx.x >> 6);
    if (row >= M) return;
    float4 v = ((const float4*)(x + (size_t)row * 256))[lane];
    float s = v.x + v.y + v.z + v.w;
    #pragma unroll
    for (int m = 32; m >= 1; m >>= 1) s += __shfl_xor(s, m);
    float mean = s * 0.00390625f;
    float dx = v.x - mean, dy = v.y - mean, dz = v.z - mean, dw = v.w - mean;
    float vs = dx * dx + dy * dy + dz * dz + dw * dw;
    #pragma unroll
    for (int m = 32; m >= 1; m >>= 1) vs += __shfl_xor(vs, m);
    float rs = rsqrtf(vs * 0.00390625f + 1e-6f);
    f16x4 o = {(_Float16)(dx * rs), (_Float16)(dy * rs), (_Float16)(dz * rs), (_Float16)(dw * rs)};
    ((f16x4*)(y + (size_t)row * 256))[lane] = o;
}

// ---------------------------------------------------------------------------
// kNN — branchless 2-pass threshold algorithm.
// Block = 256 threads = 16 queries x 16 parts; part p scans candidates
// j === p (mod 16). Pass A: per-part top-2 (branchless). tau = 16th-smallest
// of the 32 part-{m0,m1} values (provable upper bound of true 16th distance).
// Pass B: push all d2 <= tau to an LDS buffer (LDS atomics). Exact top-16
// selection with (d2, index) ordering. d2 in reference order, contract off.
// ---------------------------------------------------------------------------
#define CH 1024
#define BUFCAP 320
__global__ __launch_bounds__(256)
void knn_k(const float* __restrict__ coors, int* __restrict__ idxp,
           float* __restrict__ rbfp, float* __restrict__ rup)
{
    #pragma clang fp contract(off)
    __shared__ float cf[CH * 3];
    __shared__ float pm[16][32];
    __shared__ float tauS[16];
    __shared__ int   cnt[16];
    __shared__ float bufD[16][BUFCAP];
    __shared__ int   bufJ[16][BUFCAP];
    __shared__ float selD[16][16];
    __shared__ int   selJ[16][16];

    const int t = threadIdx.x;
    const int qq = t & 15;
    const int part = t >> 4;
    const int n = blockIdx.x * 16 + qq;
    const float qx = coors[n * 3 + 0], qy = coors[n * 3 + 1], qz = coors[n * 3 + 2];

    // ---- pass A: branchless per-part top-2 ----
    float m0 = 3.4e38f, m1 = 3.4e38f;
    for (int cbase = 0; cbase < NPTS; cbase += CH) {
        int cn = min(CH, NPTS - cbase);
        __syncthreads();
        for (int qi = t; qi < cn * 3; qi += 256) cf[qi] = coors[cbase * 3 + qi];
        __syncthreads();
        int nj = cn >> 4;
        for (int jj = 0; jj < nj; ++jj) {
            int local = jj * 16 + part;
            float dx = cf[local * 3 + 0] - qx;
            float dy = cf[local * 3 + 1] - qy;
            float dz = cf[local * 3 + 2] - qz;
            float d2 = dx * dx + dy * dy;
            d2 = d2 + dz * dz;
            bool l0 = d2 < m0;
            bool l1 = d2 < m1;
            m1 = l0 ? m0 : (l1 ? d2 : m1);
            m0 = l0 ? d2 : m0;
        }
    }
    pm[qq][part * 2] = m0;
    pm[qq][part * 2 + 1] = m1;
    if (t < 16) cnt[t] = 0;
    __syncthreads();

    // ---- tau = 16th smallest of 32 (rank-15 by (value, pos)) ----
    if (t < 16) {
        float tau = 3.4e38f;
        for (int i = 0; i < 32; ++i) {
            float v = pm[t][i];
            int c = 0;
            for (int j = 0; j < 32; ++j) {
                float vj = pm[t][j];
                c += (vj < v || (vj == v && j < i)) ? 1 : 0;
            }
            if (c == 15) tau = v;
        }
        tauS[t] = tau;
    }
    __syncthreads();
    const float tau = tauS[qq];

    // ---- pass B: collect qualifying candidates ----
    for (int cbase = 0; cbase < NPTS; cbase += CH) {
        int cn = min(CH, NPTS - cbase);
        __syncthreads();
        for (int qi = t; qi < cn * 3; qi += 256) cf[qi] = coors[cbase * 3 + qi];
        __syncthreads();
        int nj = cn >> 4;
        for (int jj = 0; jj < nj; ++jj) {
            int local = jj * 16 + part;
            float dx = cf[local * 3 + 0] - qx;
            float dy = cf[local * 3 + 1] - qy;
            float dz = cf[local * 3 + 2] - qz;
            float d2 = dx * dx + dy * dy;
            d2 = d2 + dz * dz;
            if (d2 <= tau) {
                int pos = atomicAdd(&cnt[qq], 1);
                if (pos < BUFCAP) { bufD[qq][pos] = d2; bufJ[qq][pos] = cbase + local; }
            }
        }
    }
    __syncthreads();

    // ---- exact top-16 selection (ties -> smaller index, numpy order) ----
    if (t < 16) {
        int c = min(cnt[t], BUFCAP);
        for (int m = 0; m < 16; ++m) {
            float best = 3.5e38f; int bj = 0x7fffffff, bp = 0;
            for (int i = 0; i < c; ++i) {
                float d = bufD[t][i]; int j = bufJ[t][i];
                if (d < best || (d == best && j < bj)) { best = d; bj = j; bp = i; }
            }
            selD[t][m] = best; selJ[t][m] = bj;
            bufD[t][bp] = 3.4e38f;
        }
    }
    __syncthreads();

    // ---- outputs: one (query, neighbor) pair per thread ----
    {
        int q = t >> 4, m = t & 15;
        int nn = blockIdx.x * 16 + q;
        int j = selJ[q][m];
        float d2 = selD[q][m];
        float dist = sqrtf(d2 + 1e-6f);
        float rx = coors[j * 3 + 0] - coors[nn * 3 + 0];
        float ry = coors[j * 3 + 1] - coors[nn * 3 + 1];
        float rz = coors[j * 3 + 2] - coors[nn * 3 + 2];
        idxp[nn * 16 + m] = j;
        rup[(nn * 16 + m) * 3 + 0] = rx / dist;
        rup[(nn * 16 + m) * 3 + 1] = ry / dist;
        rup[(nn * 16 + m) * 3 + 2] = rz / dist;
        #pragma unroll
        for (int r = 0; r < 16; ++r) {
            float cc = (4.0f / 15.0f) * r;
            float dd = dist - cc;
            rbfp[(size_t)nn * 256 + m * 16 + r] = expf(-dd * dd * 8.0f);
        }
    }
}

// ---------------------------------------------------------------------------
// Fused attention: one block per node, 128 threads. f16 P/V1 inputs, fp32 math.
// P per node: [q(128) | k(128) | v0(128) | vr(128)] f16.
// V1 per node: [v=0 (128) | v=1 | v=2] f16. O0/O1 f16 outputs.
// ---------------------------------------------------------------------------
__global__ __launch_bounds__(128)
void attn_k(const _Float16* __restrict__ P, const _Float16* __restrict__ V1,
            const float* __restrict__ rbf, const float* __restrict__ ru,
            const int* __restrict__ idx,
            const float* __restrict__ We, const float* __restrict__ Wer,
            _Float16* __restrict__ O0, _Float16* __restrict__ O1)
{
    const int n = blockIdx.x;
    const int hd = threadIdx.x;
    const int h = hd >> 5;
    __shared__ float WeS[16][128], WerS[16][128];
    __shared__ float rbfS[16][16];
    __shared__ float ruS[16][4];
    __shared__ int   idxS[16];
    __shared__ float logitsS[4][16];
    __shared__ float attnS[4][16];

    #pragma unroll
    for (int r = 0; r < 16; ++r) {
        WeS[r][hd]  = We[r * 128 + hd];
        WerS[r][hd] = Wer[r * 128 + hd];
    }
    ((float*)rbfS)[hd]       = rbf[(size_t)n * 256 + hd];
    ((float*)rbfS)[hd + 128] = rbf[(size_t)n * 256 + 128 + hd];
    if (hd < 16) idxS[hd] = idx[n * 16 + hd];
    if (hd < 48) ruS[hd / 3][hd % 3] = ru[n * 48 + hd];
    float q = (float)P[(size_t)n * 512 + hd];
    __syncthreads();

    #pragma unroll 4
    for (int k = 0; k < 16; ++k) {
        int j = idxS[k];
        float kv = (float)P[(size_t)j * 512 + 128 + hd];
        float racc = 0.f;
        #pragma unroll
        for (int r = 0; r < 16; ++r) racc += rbfS[k][r] * WeS[r][hd];
        kv += racc;
        float prod = q * kv;
        prod += __shfl_xor(prod, 1);
        prod += __shfl_xor(prod, 2);
        prod += __shfl_xor(prod, 4);
        prod += __shfl_xor(prod, 8);
        prod += __shfl_xor(prod, 16);
        if ((hd & 31) == 0) logitsS[h][k] = prod * 0.17677669529663687f;
    }
    __syncthreads();

    {
        float mx = -1e30f;
        #pragma unroll
        for (int k = 0; k < 16; ++k) mx = fmaxf(mx, logitsS[h][k]);
        float aw[16]; float s = 0.f;
        #pragma unroll
        for (int k = 0; k < 16; ++k) { aw[k] = expf(logitsS[h][k] - mx); s += aw[k]; }
        float inv = 1.f / s;
        if ((hd & 31) == 0) {
            #pragma unroll
            for (int k = 0; k < 16; ++k) attnS[h][k] = aw[k] * inv;
        }
    }
    __syncthreads();

    float o0 = 0.f, o1x = 0.f, o1y = 0.f, o1z = 0.f;
    #pragma unroll 4
    for (int k = 0; k < 16; ++k) {
        int j = idxS[k];
        float a = attnS[h][k];
        const _Float16* pj = P + (size_t)j * 512;
        float v0 = (float)pj[256 + hd];
        float ge = (float)pj[384 + hd];
        float racc = 0.f;
        #pragma unroll
        for (int r = 0; r < 16; ++r) racc += rbfS[k][r] * WerS[r][hd];
        ge += racc;
        const _Float16* vj = V1 + (size_t)j * 384;
        o0  += a * v0;
        o1x += a * ((float)vj[hd]       + ge * ruS[k][0]);
        o1y += a * ((float)vj[128 + hd] + ge * ruS[k][1]);
        o1z += a * ((float)vj[256 + hd] + ge * ruS[k][2]);
    }
    O0[(size_t)n * 128 + hd] = (_Float16)o0;
    _Float16* o1p = O1 + (size_t)n * 384;
    o1p[hd] = (_Float16)o1x; o1p[128 + hd] = (_Float16)o1y; o1p[256 + hd] = (_Float16)o1z;
}

// ---------------------------------------------------------------------------
__global__ __launch_bounds__(256)
void vecout_k(const float* __restrict__ f1, const float* __restrict__ wv,
              float* __restrict__ out2)
{
    int row = blockIdx.x * 256 + threadIdx.x;
    if (row >= NPTS * 3) return;
    const float4* fr = (const float4*)(f1 + (size_t)row * 64);
    const float4* w4 = (const float4*)wv;
    float s = 0.f;
    #pragma unroll
    for (int c = 0; c < 16; ++c) {
        float4 a = fr[c], b = w4[c];
        s += a.x * b.x + a.y * b.y + a.z * b.z + a.w * b.w;
    }
    out2[row] = s;
}

// ---------------------------------------------------------------------------
extern "C" void kernel_launch(void* const* d_in, const int* in_sizes, int n_in,
                              void* d_out, int out_size, void* d_ws, size_t ws_size,
                              hipStream_t stream)
{
    (void)in_sizes; (void)n_in; (void)out_size; (void)ws_size;
    const float* feats = (const float*)d_in[0];
    const float* coors = (const float*)d_in[1];
    const float* Wemb = (const float*)d_in[3];
    const float* Wq   = (const float*)d_in[4];
    const float* Wk   = (const float*)d_in[5];
    const float* Wv0  = (const float*)d_in[6];
    const float* Wvr  = (const float*)d_in[7];
    const float* We   = (const float*)d_in[8];
    const float* Wer  = (const float*)d_in[9];
    const float* Wv1  = (const float*)d_in[10];
    const float* Wo0  = (const float*)d_in[11];
    const float* Wo1  = (const float*)d_in[12];
    const float* Wf1  = (const float*)d_in[13];
    const float* bf1  = (const float*)d_in[14];
    const float* Wf2  = (const float*)d_in[15];
    const float* bf2  = (const float*)d_in[16];
    const float* Wg   = (const float*)d_in[17];
    const float* Wvff = (const float*)d_in[18];
    const float* Ws   = (const float*)d_in[19];
    const float* bs   = (const float*)d_in[20];
    const float* wv   = (const float*)d_in[21];
    float* out = (float*)d_out;

    char* ws = (char*)d_ws;
    size_t off = 0;
    auto carve = [&](size_t bytes) -> char* {
        char* p = ws + off;
        off += (bytes + 255) & ~(size_t)255;
        return p;
    };
    int*      idxp   = (int*)      carve((size_t)NPTS * 16 * 4);
    float*    rbfp   = (float*)    carve((size_t)NPTS * 256 * 4);
    float*    rup    = (float*)    carve((size_t)NPTS * 48 * 4);
    float*    f0     = (float*)    carve((size_t)NPTS * 256 * 4);
    float*    f1     = (float*)    carve((size_t)NPTS * 192 * 4);
    float*    gt     = (float*)    carve((size_t)NPTS * 64 * 4);
    _Float16* f0n_h  = (_Float16*) carve((size_t)NPTS * 256 * 2);
    _Float16* f0h    = (_Float16*) carve((size_t)NPTS * 256 * 2);
    _Float16* f1h    = (_Float16*) carve((size_t)NPTS * 192 * 2);
    _Float16* O1h    = (_Float16*) carve((size_t)NPTS * 384 * 2);
    _Float16* featsh = (_Float16*) carve((size_t)NPTS * 256 * 2);
    // Ph + V1h + O0h are contiguous (10.24 + 7.68 + 2.56 MB = 20.48 MB);
    // Hbh (10000 x 1024 f16 = 20.48 MB) aliases them (dead by FFN time).
    _Float16* Ph     = (_Float16*) carve((size_t)NPTS * 512 * 2);
    _Float16* V1h    = (_Float16*) carve((size_t)NPTS * 384 * 2);
    _Float16* O0h    = (_Float16*) carve((size_t)NPTS * 128 * 2);
    _Float16* Hbh    = Ph;
    _Float16* WembT  = (_Float16*) carve(65536 * 2);
    _Float16* WqkvrT = (_Float16*) carve(4 * 131072 * 2);
    _Float16* Wv1T   = (_Float16*) carve(4 * 8192 * 2);
    _Float16* Wo0T   = (_Float16*) carve(4 * 32768 * 2);
    _Float16* Wo1T   = (_Float16*) carve(4 * 8192 * 2);
    _Float16* WfgT   = (_Float16*) carve(4 * 278528 * 2);   // [Wf1 (1024) ; Wg (64)] x 256
    _Float16* Wf2T   = (_Float16*) carve(4 * 262144 * 2);
    _Float16* WvffT  = (_Float16*) carve(4 * 4096 * 2);
    _Float16* WsT    = (_Float16*) carve(65536 * 2);

    // ---- weight transpose-convert (46 descriptors, one launch) ----
    TXA ta;
    int blk = 0, di = 0;
    auto addt = [&](const float* s, _Float16* d, int Ks, int Ns) {
        ta.t[di].src = s; ta.t[di].dst = d; ta.t[di].K = Ks; ta.t[di].N = Ns;
        ta.t[di].blk0 = blk; blk += (Ks / 32) * (Ns / 32); ++di;
    };
    addt(Wemb, WembT, 256, 256);
    for (int l = 0; l < 4; ++l) {
        addt(Wq  + l * 32768, WqkvrT + (size_t)l * 131072 +     0, 256, 128);
        addt(Wk  + l * 32768, WqkvrT + (size_t)l * 131072 + 32768, 256, 128);
        addt(Wv0 + l * 32768, WqkvrT + (size_t)l * 131072 + 65536, 256, 128);
        addt(Wvr + l * 32768, WqkvrT + (size_t)l * 131072 + 98304, 256, 128);
    }
    for (int l = 0; l < 4; ++l) addt(Wv1  + l * 8192,   Wv1T  + l * 8192,   64, 128);
    for (int l = 0; l < 4; ++l) addt(Wo0  + l * 32768,  Wo0T  + l * 32768,  128, 256);
    for (int l = 0; l < 4; ++l) addt(Wo1  + l * 8192,   Wo1T  + l * 8192,   128, 64);
    for (int l = 0; l < 4; ++l) {
        addt(Wf1 + l * 262144, WfgT + (size_t)l * 278528,          256, 1024);
        addt(Wg  + l * 16384,  WfgT + (size_t)l * 278528 + 262144, 256, 64);
    }
    for (int l = 0; l < 4; ++l) addt(Wf2  + l * 262144, Wf2T  + l * 262144, 1024, 256);
    for (int l = 0; l < 4; ++l) addt(Wvff + l * 4096,   WvffT + l * 4096,   64, 64);
    addt(Ws, WsT, 256, 256);
    tconv_k<<<blk, 256, 0, stream>>>(ta);

    cvt_k<<<(NPTS * 256 / 8 + 255) / 256, 256, 0, stream>>>(feats, featsh, NPTS * 256 / 8);
    knn_k<<<625, 256, 0, stream>>>(coors, idxp, rbfp, rup);

    // f0 = feats @ Wemb
    hgemm_k<0,false,false,false,0,64><<<dim3(4,157),256,0,stream>>>(featsh,256,WembT,nullptr,nullptr,nullptr,f0,nullptr,256,NPTS,256,256);
    hipMemsetAsync(f1, 0, (size_t)NPTS * 192 * 4, stream);
    hipMemsetAsync(f1h, 0, (size_t)NPTS * 192 * 2, stream);

    for (int l = 0; l < 4; ++l) {
        ln_k<<<2500,256,0,stream>>>(f0, f0n_h, NPTS);
        // Ph = f16( f0n @ [Wq|Wk|Wv0|Wvr] )
        hgemm_k<0,false,false,false,1,128><<<dim3(4,157),256,0,stream>>>(f0n_h,256,WqkvrT+(size_t)l*131072,nullptr,nullptr,nullptr,nullptr,Ph,512,NPTS,512,256);
        // V1h = f16( f1 @ Wv1 )
        hgemm_k<0,false,false,false,1,64><<<dim3(2,469),256,0,stream>>>(f1h,64,Wv1T+l*8192,nullptr,nullptr,nullptr,nullptr,V1h,128,NPTS*3,128,64);
        attn_k<<<NPTS,128,0,stream>>>(Ph, V1h, rbfp, rup, idxp, We + l*2048, Wer + l*2048, O0h, O1h);
        // f0 += O0 @ Wo0
        hgemm_k<0,true,false,false,0,64><<<dim3(4,157),256,0,stream>>>(O0h,128,Wo0T+l*32768,nullptr,nullptr,nullptr,f0,nullptr,256,NPTS,256,128);
        // f1 += O1 @ Wo1 (+ f16 mirror)
        hgemm_k<0,true,false,false,2,64><<<dim3(1,469),256,0,stream>>>(O1h,128,Wo1T+l*8192,nullptr,nullptr,nullptr,f1,f1h,64,NPTS*3,64,128);
        ln_k<<<2500,256,0,stream>>>(f0, f0n_h, NPTS);
        // Hb = gelu(f0n @ Wf1 + bf1) (f16), gate = sigmoid(f0n @ Wg) — fused
        hgemm_k<3,false,true,false,1,128><<<dim3(9,157),256,0,stream>>>(f0n_h,256,WfgT+(size_t)l*278528,bf1+l*1024,nullptr,gt,nullptr,Hbh,1024,NPTS,1088,256);
        // f0 += Hb @ Wf2 + bf2 (last layer also writes f0h)
        if (l < 3)
            hgemm_k<0,true,true,false,0,64><<<dim3(4,157),256,0,stream>>>(Hbh,1024,Wf2T+(size_t)l*262144,bf2+l*256,nullptr,nullptr,f0,nullptr,256,NPTS,256,1024);
        else
            hgemm_k<0,true,true,false,2,64><<<dim3(4,157),256,0,stream>>>(Hbh,1024,Wf2T+(size_t)l*262144,bf2+l*256,nullptr,nullptr,f0,f0h,256,NPTS,256,1024);
        // f1 += (f1 @ Wvff) * gate (+ f16 mirror)
        hgemm_k<0,true,false,true,2,64><<<dim3(1,469),256,0,stream>>>(f1h,64,WvffT+l*4096,nullptr,gt,nullptr,f1,f1h,64,NPTS*3,64,64);
    }

    // pred_scalar = f0 @ Ws + bs
    hgemm_k<0,false,true,false,0,64><<<dim3(4,157),256,0,stream>>>(f0h,256,WsT,bs,nullptr,nullptr,out,nullptr,256,NPTS,256,256);
    // pred_vector
    vecout_k<<<118,256,0,stream>>>(f1, wv, out + (size_t)NPTS * 256);
}

// Round 4
// 1054.308 us; speedup vs baseline: 2.8471x; 1.1983x over previous
//
#include <hip/hip_runtime.h>
#include <math.h>

// ---------------------------------------------------------------------------
// EquiformerPointHead — round 4: ILP/occupancy-fixed kNN (float4 LDS, 512 thr,
// parallel selection), BK=64 GEMM (half the barriers).
// N=10000, C0=256, C1=64, DEPTH=4, HEADS=4, DH=32, H=128, K=16, R=16
// ---------------------------------------------------------------------------

#define NPTS 10000

using f16x8 = __attribute__((ext_vector_type(8))) _Float16;
using f16x4 = __attribute__((ext_vector_type(4))) _Float16;
using f32x4 = __attribute__((ext_vector_type(4))) float;

__device__ __forceinline__ float gelu_f(float x) {
    float u = 0.7978845608028654f * (x + 0.044715f * x * x * x);
    return 0.5f * x * (1.0f + tanhf(u));
}
__device__ __forceinline__ float sigmoid_f(float x) {
    return 1.0f / (1.0f + expf(-x));
}
__device__ __forceinline__ f16x8 zero8() {
    f16x8 v;
    #pragma unroll
    for (int i = 0; i < 8; ++i) v[i] = (_Float16)0.f;
    return v;
}

// ---------------------------------------------------------------------------
// fp16 MFMA GEMM: C[MxN] = epi(A[MxK] @ Bt[NxK]^T), fp32 accumulate.
// BM=64, BN in {64,128}, BK=64 (K%64==0 for all call sites), 256 thr = 4 waves.
// ACT: 0 none, 1 gelu, 2 sigmoid, 3 split(col<1024: gelu->Ch f16,
//      else sigmoid->gout f32 [row*64+col-1024]).
// ADD: +=C. BIAS: +bias[col] (ACT3: only col<1024). GATED: *gate[(row/3)*64+col].
// OUT16: 0 f32 only, 1 f16 only, 2 both.
// LDS 16B-slot swizzle over 8 slots: slot' = s ^ (row&7)  (2-way on reads = free).
// ---------------------------------------------------------------------------
template<int ACT, bool ADD, bool BIAS, bool GATED, int OUT16, int BN>
__global__ __launch_bounds__(256)
void hgemm_k(const _Float16* __restrict__ A, int lda,
             const _Float16* __restrict__ Bt,
             const float* __restrict__ bias,
             const float* __restrict__ gate,
             float* __restrict__ gout,
             float* __restrict__ C, _Float16* __restrict__ Ch, int ldc,
             int M, int N, int K)
{
    constexpr int NI = BN / 32;           // n-tiles per wave
    __shared__ _Float16 As[64 * 64];
    __shared__ _Float16 Bs[BN * 64];
    const int bm = blockIdx.y * 64;
    const int bn = blockIdx.x * BN;
    const int tid = threadIdx.x;
    const int lane = tid & 63;
    const int wid = tid >> 6;
    const int wr = wid >> 1, wc = wid & 1;
    const int l15 = lane & 15, lg = lane >> 4;

    f32x4 acc[2][NI];
    #pragma unroll
    for (int mi = 0; mi < 2; ++mi)
        #pragma unroll
        for (int ni = 0; ni < NI; ++ni)
            #pragma unroll
            for (int r = 0; r < 4; ++r) acc[mi][ni][r] = 0.f;

    for (int kt = 0; kt < K; kt += 64) {
        #pragma unroll
        for (int i = 0; i < 2; ++i) {   // stage A: 64 rows x 8 slots
            int c = tid + i * 256;
            int row = c >> 3, s = c & 7;
            f16x8 v = zero8();
            if (bm + row < M) v = *(const f16x8*)(A + (size_t)(bm + row) * lda + kt + s * 8);
            ((f16x8*)As)[row * 8 + (s ^ (row & 7))] = v;
        }
        #pragma unroll
        for (int i = 0; i < BN / 32; ++i) {  // stage B: BN rows x 8 slots
            int c = tid + i * 256;
            int row = c >> 3, s = c & 7;
            f16x8 v = zero8();
            if (bn + row < N) v = *(const f16x8*)(Bt + (size_t)(bn + row) * K + kt + s * 8);
            ((f16x8*)Bs)[row * 8 + (s ^ (row & 7))] = v;
        }
        __syncthreads();
        f16x8 af[2][2], bf[NI][2];
        #pragma unroll
        for (int mi = 0; mi < 2; ++mi) {
            int row = wr * 32 + mi * 16 + l15;
            #pragma unroll
            for (int kk = 0; kk < 2; ++kk)
                af[mi][kk] = ((const f16x8*)As)[row * 8 + ((kk * 4 + lg) ^ (row & 7))];
        }
        #pragma unroll
        for (int ni = 0; ni < NI; ++ni) {
            int row = wc * (BN / 2) + ni * 16 + l15;
            #pragma unroll
            for (int kk = 0; kk < 2; ++kk)
                bf[ni][kk] = ((const f16x8*)Bs)[row * 8 + ((kk * 4 + lg) ^ (row & 7))];
        }
        #pragma unroll
        for (int kk = 0; kk < 2; ++kk)
            #pragma unroll
            for (int mi = 0; mi < 2; ++mi)
                #pragma unroll
                for (int ni = 0; ni < NI; ++ni)
                    acc[mi][ni] = __builtin_amdgcn_mfma_f32_16x16x32_f16(af[mi][kk], bf[ni][kk], acc[mi][ni], 0, 0, 0);
        __syncthreads();
    }

    // epilogue: C/D layout col=lane&15, row=(lane>>4)*4+reg
    #pragma unroll
    for (int mi = 0; mi < 2; ++mi) {
        #pragma unroll
        for (int ni = 0; ni < NI; ++ni) {
            int col = bn + wc * (BN / 2) + ni * 16 + l15;
            #pragma unroll
            for (int r = 0; r < 4; ++r) {
                int row = bm + wr * 32 + mi * 16 + lg * 4 + r;
                if (row < M && col < N) {
                    float v = acc[mi][ni][r];
                    if (ACT == 3) {
                        if (col < 1024) {
                            if (BIAS) v += bias[col];
                            v = gelu_f(v);
                            Ch[(size_t)row * ldc + col] = (_Float16)v;
                        } else {
                            gout[(size_t)row * 64 + (col - 1024)] = sigmoid_f(v);
                        }
                    } else {
                        if (BIAS) v += bias[col];
                        if (ACT == 1) v = gelu_f(v);
                        if (ACT == 2) v = sigmoid_f(v);
                        if (GATED) v *= gate[(size_t)(row / 3) * 64 + col];
                        size_t o = (size_t)row * ldc + col;
                        if (ADD) v += C[o];
                        if (OUT16 != 1) C[o] = v;
                        if (OUT16 >= 1) Ch[o] = (_Float16)v;
                    }
                }
            }
        }
    }
}

// ---------------------------------------------------------------------------
// Batched weight transpose-convert: src fp32 [K][N] -> dst f16 [N][K].
// ---------------------------------------------------------------------------
struct TXT { const float* src; _Float16* dst; int K, N, blk0; };
struct TXA { TXT t[46]; };

__global__ __launch_bounds__(256)
void tconv_k(TXA g)
{
    __shared__ float tile[32][33];
    int b = blockIdx.x;
    int d = 0;
    while (d < 45 && b >= g.t[d + 1].blk0) ++d;
    int local = b - g.t[d].blk0;
    const float* src = g.t[d].src;
    _Float16* dst = g.t[d].dst;
    int K = g.t[d].K, N = g.t[d].N;
    int ntj = N >> 5;
    int ti = local / ntj;
    int tj = local - ti * ntj;
    int tx = threadIdx.x & 31, ty = threadIdx.x >> 5;
    #pragma unroll
    for (int i = 0; i < 4; ++i)
        tile[ty + i * 8][tx] = src[(size_t)(ti * 32 + ty + i * 8) * N + tj * 32 + tx];
    __syncthreads();
    #pragma unroll
    for (int i = 0; i < 4; ++i)
        dst[(size_t)(tj * 32 + ty + i * 8) * K + ti * 32 + tx] = (_Float16)tile[tx][ty + i * 8];
}

// fp32 -> f16 elementwise (8 per thread)
__global__ __launch_bounds__(256)
void cvt_k(const float* __restrict__ src, _Float16* __restrict__ dst, int n8)
{
    int i = blockIdx.x * 256 + threadIdx.x;
    if (i >= n8) return;
    float4 a = ((const float4*)src)[2 * i];
    float4 b = ((const float4*)src)[2 * i + 1];
    f16x8 o = {(_Float16)a.x, (_Float16)a.y, (_Float16)a.z, (_Float16)a.w,
               (_Float16)b.x, (_Float16)b.y, (_Float16)b.z, (_Float16)b.w};
    ((f16x8*)dst)[i] = o;
}

// ---------------------------------------------------------------------------
// LayerNorm over rows of 256, f16 output.
// ---------------------------------------------------------------------------
__global__ __launch_bounds__(256)
void ln_k(const float* __restrict__ x, _Float16* __restrict__ y, int M)
{
    int lane = threadIdx.x & 63;
    int row = blockIdx.x * 4 + (threadIdx.x >> 6);
    if (row >= M) return;
    float4 v = ((const float4*)(x + (size_t)row * 256))[lane];
    float s = v.x + v.y + v.z + v.w;
    #pragma unroll
    for (int m = 32; m >= 1; m >>= 1) s += __shfl_xor(s, m);
    float mean = s * 0.00390625f;
    float dx = v.x - mean, dy = v.y - mean, dz = v.z - mean, dw = v.w - mean;
    float vs = dx * dx + dy * dy + dz * dz + dw * dw;
    #pragma unroll
    for (int m = 32; m >= 1; m >>= 1) vs += __shfl_xor(vs, m);
    float rs = rsqrtf(vs * 0.00390625f + 1e-6f);
    f16x4 o = {(_Float16)(dx * rs), (_Float16)(dy * rs), (_Float16)(dz * rs), (_Float16)(dw * rs)};
    ((f16x4*)(y + (size_t)row * 256))[lane] = o;
}

// ---------------------------------------------------------------------------
// kNN — branchless 2-pass threshold algorithm, latency-optimized.
// Block = 512 threads = 16 queries x 32 parts. Coords staged as float4 in LDS
// (one ds_read_b128/candidate, broadcast within 16-lane groups, conflict-free).
// 4-candidate unroll for memory-level parallelism. Pass A: per-part top-2
// (branchless) -> tau = 16th smallest of 64 (parallel rank). Pass B: collect
// d2 <= tau. Parallel rank-based exact top-16 with (d2,index) order.
// d2 in reference order, contract off.
// ---------------------------------------------------------------------------
#define CH 1024
#define BUFCAP 192
__global__ __launch_bounds__(512)
void knn_k(const float* __restrict__ coors, int* __restrict__ idxp,
           float* __restrict__ rbfp, float* __restrict__ rup)
{
    #pragma clang fp contract(off)
    __shared__ float4 cf4[CH];
    __shared__ float pm[16][64];
    __shared__ float tauS[16];
    __shared__ int   cnt[16];
    __shared__ float bufD[16][BUFCAP];
    __shared__ int   bufJ[16][BUFCAP];
    __shared__ float selD[16][16];
    __shared__ int   selJ[16][16];

    const int t = threadIdx.x;
    const int qq = t & 15;
    const int part = t >> 4;              // 0..31
    const int n = blockIdx.x * 16 + qq;
    const float qx = coors[n * 3 + 0], qy = coors[n * 3 + 1], qz = coors[n * 3 + 2];

    // ---- pass A: branchless per-part top-2 ----
    float m0 = 3.4e38f, m1 = 3.4e38f;
    for (int cbase = 0; cbase < NPTS; cbase += CH) {
        int cn = min(CH, NPTS - cbase);
        __syncthreads();
        for (int i = t; i < cn; i += 512)
            cf4[i] = make_float4(coors[(cbase + i) * 3 + 0], coors[(cbase + i) * 3 + 1],
                                 coors[(cbase + i) * 3 + 2], 0.f);
        __syncthreads();
        for (int base = 0; base < cn; base += 128) {
            float d2v[4];
            #pragma unroll
            for (int u = 0; u < 4; ++u) {
                int local = base + u * 32 + part;
                float4 c = cf4[local];
                float dx = c.x - qx;
                float dy = c.y - qy;
                float dz = c.z - qz;
                float d2 = dx * dx + dy * dy;
                d2 = d2 + dz * dz;
                d2v[u] = (local < cn) ? d2 : 3.4e38f;
            }
            #pragma unroll
            for (int u = 0; u < 4; ++u) {
                float d2 = d2v[u];
                bool l0 = d2 < m0;
                bool l1 = d2 < m1;
                m1 = l0 ? m0 : (l1 ? d2 : m1);
                m0 = l0 ? d2 : m0;
            }
        }
    }
    pm[qq][part * 2] = m0;
    pm[qq][part * 2 + 1] = m1;
    if (t < 16) cnt[t] = 0;
    __syncthreads();

    // ---- tau = 16th smallest of 64 (rank-15 by (value, pos)); parallel ----
    #pragma unroll
    for (int rep = 0; rep < 2; ++rep) {
        int i = part + rep * 32;
        float v = pm[qq][i];
        int c = 0;
        for (int j = 0; j < 64; ++j) {
            float vj = pm[qq][j];
            c += (vj < v || (vj == v && j < i)) ? 1 : 0;
        }
        if (c == 15) tauS[qq] = v;
    }
    __syncthreads();
    const float tau = tauS[qq];

    // ---- pass B: collect qualifying candidates ----
    for (int cbase = 0; cbase < NPTS; cbase += CH) {
        int cn = min(CH, NPTS - cbase);
        __syncthreads();
        for (int i = t; i < cn; i += 512)
            cf4[i] = make_float4(coors[(cbase + i) * 3 + 0], coors[(cbase + i) * 3 + 1],
                                 coors[(cbase + i) * 3 + 2], 0.f);
        __syncthreads();
        for (int base = 0; base < cn; base += 128) {
            #pragma unroll
            for (int u = 0; u < 4; ++u) {
                int local = base + u * 32 + part;
                float4 c = cf4[local];
                float dx = c.x - qx;
                float dy = c.y - qy;
                float dz = c.z - qz;
                float d2 = dx * dx + dy * dy;
                d2 = d2 + dz * dz;
                if (local < cn && d2 <= tau) {
                    int pos = atomicAdd(&cnt[qq], 1);
                    if (pos < BUFCAP) { bufD[qq][pos] = d2; bufJ[qq][pos] = cbase + local; }
                }
            }
        }
    }
    __syncthreads();

    // ---- exact top-16: parallel rank-based placement (ties -> smaller idx) ----
    {
        int c = min(cnt[qq], BUFCAP);
        for (int i = part; i < c; i += 32) {
            float d = bufD[qq][i]; int j = bufJ[qq][i];
            int rank = 0;
            for (int k = 0; k < c; ++k) {
                float dk = bufD[qq][k]; int jk = bufJ[qq][k];
                rank += (dk < d || (dk == d && jk < j)) ? 1 : 0;
            }
            if (rank < 16) { selD[qq][rank] = d; selJ[qq][rank] = j; }
        }
    }
    __syncthreads();

    // ---- outputs: one (query, neighbor) pair per thread (first 256) ----
    if (t < 256) {
        int q = t >> 4, m = t & 15;
        int nn = blockIdx.x * 16 + q;
        int j = selJ[q][m];
        float d2 = selD[q][m];
        float dist = sqrtf(d2 + 1e-6f);
        float rx = coors[j * 3 + 0] - coors[nn * 3 + 0];
        float ry = coors[j * 3 + 1] - coors[nn * 3 + 1];
        float rz = coors[j * 3 + 2] - coors[nn * 3 + 2];
        idxp[nn * 16 + m] = j;
        rup[(nn * 16 + m) * 3 + 0] = rx / dist;
        rup[(nn * 16 + m) * 3 + 1] = ry / dist;
        rup[(nn * 16 + m) * 3 + 2] = rz / dist;
        #pragma unroll
        for (int r = 0; r < 16; ++r) {
            float cc = (4.0f / 15.0f) * r;
            float dd = dist - cc;
            rbfp[(size_t)nn * 256 + m * 16 + r] = expf(-dd * dd * 8.0f);
        }
    }
}

// ---------------------------------------------------------------------------
// Fused attention: one block per node, 128 threads. f16 P/V1 inputs, fp32 math.
// P per node: [q(128) | k(128) | v0(128) | vr(128)] f16.
// V1 per node: [v=0 (128) | v=1 | v=2] f16. O0/O1 f16 outputs.
// ---------------------------------------------------------------------------
__global__ __launch_bounds__(128)
void attn_k(const _Float16* __restrict__ P, const _Float16* __restrict__ V1,
            const float* __restrict__ rbf, const float* __restrict__ ru,
            const int* __restrict__ idx,
            const float* __restrict__ We, const float* __restrict__ Wer,
            _Float16* __restrict__ O0, _Float16* __restrict__ O1)
{
    const int n = blockIdx.x;
    const int hd = threadIdx.x;
    const int h = hd >> 5;
    __shared__ float WeS[16][128], WerS[16][128];
    __shared__ float rbfS[16][16];
    __shared__ float ruS[16][4];
    __shared__ int   idxS[16];
    __shared__ float logitsS[4][16];
    __shared__ float attnS[4][16];

    #pragma unroll
    for (int r = 0; r < 16; ++r) {
        WeS[r][hd]  = We[r * 128 + hd];
        WerS[r][hd] = Wer[r * 128 + hd];
    }
    ((float*)rbfS)[hd]       = rbf[(size_t)n * 256 + hd];
    ((float*)rbfS)[hd + 128] = rbf[(size_t)n * 256 + 128 + hd];
    if (hd < 16) idxS[hd] = idx[n * 16 + hd];
    if (hd < 48) ruS[hd / 3][hd % 3] = ru[n * 48 + hd];
    float q = (float)P[(size_t)n * 512 + hd];
    __syncthreads();

    #pragma unroll 4
    for (int k = 0; k < 16; ++k) {
        int j = idxS[k];
        float kv = (float)P[(size_t)j * 512 + 128 + hd];
        float racc = 0.f;
        #pragma unroll
        for (int r = 0; r < 16; ++r) racc += rbfS[k][r] * WeS[r][hd];
        kv += racc;
        float prod = q * kv;
        prod += __shfl_xor(prod, 1);
        prod += __shfl_xor(prod, 2);
        prod += __shfl_xor(prod, 4);
        prod += __shfl_xor(prod, 8);
        prod += __shfl_xor(prod, 16);
        if ((hd & 31) == 0) logitsS[h][k] = prod * 0.17677669529663687f;
    }
    __syncthreads();

    {
        float mx = -1e30f;
        #pragma unroll
        for (int k = 0; k < 16; ++k) mx = fmaxf(mx, logitsS[h][k]);
        float aw[16]; float s = 0.f;
        #pragma unroll
        for (int k = 0; k < 16; ++k) { aw[k] = expf(logitsS[h][k] - mx); s += aw[k]; }
        float inv = 1.f / s;
        if ((hd & 31) == 0) {
            #pragma unroll
            for (int k = 0; k < 16; ++k) attnS[h][k] = aw[k] * inv;
        }
    }
    __syncthreads();

    float o0 = 0.f, o1x = 0.f, o1y = 0.f, o1z = 0.f;
    #pragma unroll 4
    for (int k = 0; k < 16; ++k) {
        int j = idxS[k];
        float a = attnS[h][k];
        const _Float16* pj = P + (size_t)j * 512;
        float v0 = (float)pj[256 + hd];
        float ge = (float)pj[384 + hd];
        float racc = 0.f;
        #pragma unroll
        for (int r = 0; r < 16; ++r) racc += rbfS[k][r] * WerS[r][hd];
        ge += racc;
        const _Float16* vj = V1 + (size_t)j * 384;
        o0  += a * v0;
        o1x += a * ((float)vj[hd]       + ge * ruS[k][0]);
        o1y += a * ((float)vj[128 + hd] + ge * ruS[k][1]);
        o1z += a * ((float)vj[256 + hd] + ge * ruS[k][2]);
    }
    O0[(size_t)n * 128 + hd] = (_Float16)o0;
    _Float16* o1p = O1 + (size_t)n * 384;
    o1p[hd] = (_Float16)o1x; o1p[128 + hd] = (_Float16)o1y; o1p[256 + hd] = (_Float16)o1z;
}

// ---------------------------------------------------------------------------
__global__ __launch_bounds__(256)
void vecout_k(const float* __restrict__ f1, const float* __restrict__ wv,
              float* __restrict__ out2)
{
    int row = blockIdx.x * 256 + threadIdx.x;
    if (row >= NPTS * 3) return;
    const float4* fr = (const float4*)(f1 + (size_t)row * 64);
    const float4* w4 = (const float4*)wv;
    float s = 0.f;
    #pragma unroll
    for (int c = 0; c < 16; ++c) {
        float4 a = fr[c], b = w4[c];
        s += a.x * b.x + a.y * b.y + a.z * b.z + a.w * b.w;
    }
    out2[row] = s;
}

// ---------------------------------------------------------------------------
extern "C" void kernel_launch(void* const* d_in, const int* in_sizes, int n_in,
                              void* d_out, int out_size, void* d_ws, size_t ws_size,
                              hipStream_t stream)
{
    (void)in_sizes; (void)n_in; (void)out_size; (void)ws_size;
    const float* feats = (const float*)d_in[0];
    const float* coors = (const float*)d_in[1];
    const float* Wemb = (const float*)d_in[3];
    const float* Wq   = (const float*)d_in[4];
    const float* Wk   = (const float*)d_in[5];
    const float* Wv0  = (const float*)d_in[6];
    const float* Wvr  = (const float*)d_in[7];
    const float* We   = (const float*)d_in[8];
    const float* Wer  = (const float*)d_in[9];
    const float* Wv1  = (const float*)d_in[10];
    const float* Wo0  = (const float*)d_in[11];
    const float* Wo1  = (const float*)d_in[12];
    const float* Wf1  = (const float*)d_in[13];
    const float* bf1  = (const float*)d_in[14];
    const float* Wf2  = (const float*)d_in[15];
    const float* bf2  = (const float*)d_in[16];
    const float* Wg   = (const float*)d_in[17];
    const float* Wvff = (const float*)d_in[18];
    const float* Ws   = (const float*)d_in[19];
    const float* bs   = (const float*)d_in[20];
    const float* wv   = (const float*)d_in[21];
    float* out = (float*)d_out;

    char* ws = (char*)d_ws;
    size_t off = 0;
    auto carve = [&](size_t bytes) -> char* {
        char* p = ws + off;
        off += (bytes + 255) & ~(size_t)255;
        return p;
    };
    int*      idxp   = (int*)      carve((size_t)NPTS * 16 * 4);
    float*    rbfp   = (float*)    carve((size_t)NPTS * 256 * 4);
    float*    rup    = (float*)    carve((size_t)NPTS * 48 * 4);
    float*    f0     = (float*)    carve((size_t)NPTS * 256 * 4);
    float*    f1     = (float*)    carve((size_t)NPTS * 192 * 4);
    float*    gt     = (float*)    carve((size_t)NPTS * 64 * 4);
    _Float16* f0n_h  = (_Float16*) carve((size_t)NPTS * 256 * 2);
    _Float16* f0h    = (_Float16*) carve((size_t)NPTS * 256 * 2);
    _Float16* f1h    = (_Float16*) carve((size_t)NPTS * 192 * 2);
    _Float16* O1h    = (_Float16*) carve((size_t)NPTS * 384 * 2);
    _Float16* featsh = (_Float16*) carve((size_t)NPTS * 256 * 2);
    // Ph + V1h + O0h contiguous (10.24 + 7.68 + 2.56 MB = 20.48 MB);
    // Hbh (10000 x 1024 f16 = 20.48 MB) aliases them (dead by FFN time).
    _Float16* Ph     = (_Float16*) carve((size_t)NPTS * 512 * 2);
    _Float16* V1h    = (_Float16*) carve((size_t)NPTS * 384 * 2);
    _Float16* O0h    = (_Float16*) carve((size_t)NPTS * 128 * 2);
    _Float16* Hbh    = Ph;
    _Float16* WembT  = (_Float16*) carve(65536 * 2);
    _Float16* WqkvrT = (_Float16*) carve(4 * 131072 * 2);
    _Float16* Wv1T   = (_Float16*) carve(4 * 8192 * 2);
    _Float16* Wo0T   = (_Float16*) carve(4 * 32768 * 2);
    _Float16* Wo1T   = (_Float16*) carve(4 * 8192 * 2);
    _Float16* WfgT   = (_Float16*) carve(4 * 278528 * 2);   // [Wf1 (1024) ; Wg (64)] x 256
    _Float16* Wf2T   = (_Float16*) carve(4 * 262144 * 2);
    _Float16* WvffT  = (_Float16*) carve(4 * 4096 * 2);
    _Float16* WsT    = (_Float16*) carve(65536 * 2);

    // ---- weight transpose-convert (46 descriptors, one launch) ----
    TXA ta;
    int blk = 0, di = 0;
    auto addt = [&](const float* s, _Float16* d, int Ks, int Ns) {
        ta.t[di].src = s; ta.t[di].dst = d; ta.t[di].K = Ks; ta.t[di].N = Ns;
        ta.t[di].blk0 = blk; blk += (Ks / 32) * (Ns / 32); ++di;
    };
    addt(Wemb, WembT, 256, 256);
    for (int l = 0; l < 4; ++l) {
        addt(Wq  + l * 32768, WqkvrT + (size_t)l * 131072 +     0, 256, 128);
        addt(Wk  + l * 32768, WqkvrT + (size_t)l * 131072 + 32768, 256, 128);
        addt(Wv0 + l * 32768, WqkvrT + (size_t)l * 131072 + 65536, 256, 128);
        addt(Wvr + l * 32768, WqkvrT + (size_t)l * 131072 + 98304, 256, 128);
    }
    for (int l = 0; l < 4; ++l) addt(Wv1  + l * 8192,   Wv1T  + l * 8192,   64, 128);
    for (int l = 0; l < 4; ++l) addt(Wo0  + l * 32768,  Wo0T  + l * 32768,  128, 256);
    for (int l = 0; l < 4; ++l) addt(Wo1  + l * 8192,   Wo1T  + l * 8192,   128, 64);
    for (int l = 0; l < 4; ++l) {
        addt(Wf1 + l * 262144, WfgT + (size_t)l * 278528,          256, 1024);
        addt(Wg  + l * 16384,  WfgT + (size_t)l * 278528 + 262144, 256, 64);
    }
    for (int l = 0; l < 4; ++l) addt(Wf2  + l * 262144, Wf2T  + l * 262144, 1024, 256);
    for (int l = 0; l < 4; ++l) addt(Wvff + l * 4096,   WvffT + l * 4096,   64, 64);
    addt(Ws, WsT, 256, 256);
    tconv_k<<<blk, 256, 0, stream>>>(ta);

    cvt_k<<<(NPTS * 256 / 8 + 255) / 256, 256, 0, stream>>>(feats, featsh, NPTS * 256 / 8);
    knn_k<<<625, 512, 0, stream>>>(coors, idxp, rbfp, rup);

    // f0 = feats @ Wemb
    hgemm_k<0,false,false,false,0,64><<<dim3(4,157),256,0,stream>>>(featsh,256,WembT,nullptr,nullptr,nullptr,f0,nullptr,256,NPTS,256,256);
    hipMemsetAsync(f1, 0, (size_t)NPTS * 192 * 4, stream);
    hipMemsetAsync(f1h, 0, (size_t)NPTS * 192 * 2, stream);

    for (int l = 0; l < 4; ++l) {
        ln_k<<<2500,256,0,stream>>>(f0, f0n_h, NPTS);
        // Ph = f16( f0n @ [Wq|Wk|Wv0|Wvr] )
        hgemm_k<0,false,false,false,1,128><<<dim3(4,157),256,0,stream>>>(f0n_h,256,WqkvrT+(size_t)l*131072,nullptr,nullptr,nullptr,nullptr,Ph,512,NPTS,512,256);
        // V1h = f16( f1 @ Wv1 )
        hgemm_k<0,false,false,false,1,64><<<dim3(2,469),256,0,stream>>>(f1h,64,Wv1T+l*8192,nullptr,nullptr,nullptr,nullptr,V1h,128,NPTS*3,128,64);
        attn_k<<<NPTS,128,0,stream>>>(Ph, V1h, rbfp, rup, idxp, We + l*2048, Wer + l*2048, O0h, O1h);
        // f0 += O0 @ Wo0
        hgemm_k<0,true,false,false,0,64><<<dim3(4,157),256,0,stream>>>(O0h,128,Wo0T+l*32768,nullptr,nullptr,nullptr,f0,nullptr,256,NPTS,256,128);
        // f1 += O1 @ Wo1 (+ f16 mirror)
        hgemm_k<0,true,false,false,2,64><<<dim3(1,469),256,0,stream>>>(O1h,128,Wo1T+l*8192,nullptr,nullptr,nullptr,f1,f1h,64,NPTS*3,64,128);
        ln_k<<<2500,256,0,stream>>>(f0, f0n_h, NPTS);
        // Hb = gelu(f0n @ Wf1 + bf1) (f16), gate = sigmoid(f0n @ Wg) — fused
        hgemm_k<3,false,true,false,1,128><<<dim3(9,157),256,0,stream>>>(f0n_h,256,WfgT+(size_t)l*278528,bf1+l*1024,nullptr,gt,nullptr,Hbh,1024,NPTS,1088,256);
        // f0 += Hb @ Wf2 + bf2 (last layer also writes f0h)
        if (l < 3)
            hgemm_k<0,true,true,false,0,64><<<dim3(4,157),256,0,stream>>>(Hbh,1024,Wf2T+(size_t)l*262144,bf2+l*256,nullptr,nullptr,f0,nullptr,256,NPTS,256,1024);
        else
            hgemm_k<0,true,true,false,2,64><<<dim3(4,157),256,0,stream>>>(Hbh,1024,Wf2T+(size_t)l*262144,bf2+l*256,nullptr,nullptr,f0,f0h,256,NPTS,256,1024);
        // f1 += (f1 @ Wvff) * gate (+ f16 mirror)
        hgemm_k<0,true,false,true,2,64><<<dim3(1,469),256,0,stream>>>(f1h,64,WvffT+l*4096,nullptr,gt,nullptr,f1,f1h,64,NPTS*3,64,64);
    }

    // pred_scalar = f0 @ Ws + bs
    hgemm_k<0,false,true,false,0,64><<<dim3(4,157),256,0,stream>>>(f0h,256,WsT,bs,nullptr,nullptr,out,nullptr,256,NPTS,256,256);
    // pred_vector
    vecout_k<<<118,256,0,stream>>>(f1, wv, out + (size_t)NPTS * 256);
}

// Round 5
// 991.111 us; speedup vs baseline: 3.0287x; 1.0638x over previous
//
#include <hip/hip_runtime.h>
#include <math.h>

// ---------------------------------------------------------------------------
// EquiformerPointHead — round 5: global_load_lds GEMM staging, LN fused into
// consumer GEMMs, 4-node attn blocks, 1250-block kNN.
// N=10000, C0=256, C1=64, DEPTH=4, HEADS=4, DH=32, H=128, K=16, R=16
// ---------------------------------------------------------------------------

#define NPTS 10000

using f16x8 = __attribute__((ext_vector_type(8))) _Float16;
using f32x4 = __attribute__((ext_vector_type(4))) float;

__device__ __forceinline__ float gelu_f(float x) {
    float u = 0.7978845608028654f * (x + 0.044715f * x * x * x);
    return 0.5f * x * (1.0f + tanhf(u));
}
__device__ __forceinline__ float sigmoid_f(float x) {
    return 1.0f / (1.0f + expf(-x));
}
// async global->LDS: 16B per lane; LDS dest = wave-uniform base + lane*16.
__device__ __forceinline__ void gload16(const _Float16* src, _Float16* dst_lds) {
    __builtin_amdgcn_global_load_lds(
        (const __attribute__((address_space(1))) unsigned int*)(const void*)src,
        (__attribute__((address_space(3))) unsigned int*)(void*)dst_lds,
        16, 0, 0);
}

// ---------------------------------------------------------------------------
// fp16 MFMA GEMM, global_load_lds staging. C[MxN] = epi(A[MxK] @ Bt[NxK]^T).
// BM=64, BN in {64,128}, BK=64, 256 threads = 4 waves (2x2).
// LDS linear [row][8 chunks of 16B]; source col-chunk pre-swizzled by
// chunk = t ^ (row&7); reads use the same XOR (2-way bank = free).
// OOB rows/cols read garbage (stays inside d_ws) and are discarded on write.
// ---------------------------------------------------------------------------
template<int ACT, bool ADD, bool BIAS, bool GATED, int OUT16, int BN>
__global__ __launch_bounds__(256)
void hgemm_k(const _Float16* __restrict__ A, int lda,
             const _Float16* __restrict__ Bt,
             const float* __restrict__ bias,
             const float* __restrict__ gate,
             float* __restrict__ C, _Float16* __restrict__ Ch, int ldc,
             int M, int N, int K)
{
    constexpr int NI = BN / 32;
    __shared__ _Float16 As[64 * 64];
    __shared__ _Float16 Bs[BN * 64];
    const int bm = blockIdx.y * 64;
    const int bn = blockIdx.x * BN;
    const int tid = threadIdx.x;
    const int lane = tid & 63;
    const int wid = tid >> 6;
    const int wr = wid >> 1, wc = wid & 1;
    const int l15 = lane & 15, lg = lane >> 4;

    f32x4 acc[2][NI];
    #pragma unroll
    for (int mi = 0; mi < 2; ++mi)
        #pragma unroll
        for (int ni = 0; ni < NI; ++ni)
            #pragma unroll
            for (int r = 0; r < 4; ++r) acc[mi][ni][r] = 0.f;

    for (int kt = 0; kt < K; kt += 64) {
        #pragma unroll
        for (int i = 0; i < 2; ++i) {            // A: 8 segs of 1KB, 2/wave
            int seg = wid * 2 + i;
            int slot = seg * 64 + lane;
            int row = slot >> 3;
            int chunk = (slot & 7) ^ (row & 7);
            gload16(A + (size_t)(bm + row) * lda + kt + chunk * 8, As + seg * 512);
        }
        #pragma unroll
        for (int i = 0; i < BN / 32; ++i) {      // B: BN/8 segs, BN/32 per wave
            int seg = wid * (BN / 32) + i;
            int slot = seg * 64 + lane;
            int row = slot >> 3;
            int chunk = (slot & 7) ^ (row & 7);
            gload16(Bt + (size_t)(bn + row) * K + kt + chunk * 8, Bs + seg * 512);
        }
        __syncthreads();
        f16x8 af[2][2], bf[NI][2];
        #pragma unroll
        for (int mi = 0; mi < 2; ++mi) {
            int row = wr * 32 + mi * 16 + l15;
            #pragma unroll
            for (int kk = 0; kk < 2; ++kk)
                af[mi][kk] = ((const f16x8*)As)[row * 8 + ((kk * 4 + lg) ^ (row & 7))];
        }
        #pragma unroll
        for (int ni = 0; ni < NI; ++ni) {
            int row = wc * (BN / 2) + ni * 16 + l15;
            #pragma unroll
            for (int kk = 0; kk < 2; ++kk)
                bf[ni][kk] = ((const f16x8*)Bs)[row * 8 + ((kk * 4 + lg) ^ (row & 7))];
        }
        #pragma unroll
        for (int kk = 0; kk < 2; ++kk)
            #pragma unroll
            for (int mi = 0; mi < 2; ++mi)
                #pragma unroll
                for (int ni = 0; ni < NI; ++ni)
                    acc[mi][ni] = __builtin_amdgcn_mfma_f32_16x16x32_f16(af[mi][kk], bf[ni][kk], acc[mi][ni], 0, 0, 0);
        __syncthreads();
    }

    #pragma unroll
    for (int mi = 0; mi < 2; ++mi) {
        #pragma unroll
        for (int ni = 0; ni < NI; ++ni) {
            int col = bn + wc * (BN / 2) + ni * 16 + l15;
            #pragma unroll
            for (int r = 0; r < 4; ++r) {
                int row = bm + wr * 32 + mi * 16 + lg * 4 + r;
                if (row < M && col < N) {
                    float v = acc[mi][ni][r];
                    if (BIAS) v += bias[col];
                    if (ACT == 1) v = gelu_f(v);
                    if (ACT == 2) v = sigmoid_f(v);
                    if (GATED) v *= gate[(size_t)(row / 3) * 64 + col];
                    size_t o = (size_t)row * ldc + col;
                    if (ADD) v += C[o];
                    if (OUT16 != 1) C[o] = v;
                    if (OUT16 >= 1) Ch[o] = (_Float16)v;
                }
            }
        }
    }
}

// ---------------------------------------------------------------------------
// LayerNorm-fused GEMM: A = f0 fp32 [M x 256]; each block LN-normalizes its
// 64 rows once into a full-K LDS tile (f16, swizzled), then K-loops over B.
// ACT 0: Ch = A_ln @ B (f16 out).  ACT 3: col<1024 -> gelu(.+bias)->Ch;
// col in [1024,1088) -> sigmoid -> gout[row*64 + col-1024].
// ---------------------------------------------------------------------------
template<int ACT, bool BIAS, int BN>
__global__ __launch_bounds__(256)
void lngemm_k(const float* __restrict__ A,
              const _Float16* __restrict__ Bt,
              const float* __restrict__ bias,
              float* __restrict__ gout,
              _Float16* __restrict__ Ch, int ldc,
              int M, int N)
{
    constexpr int NI = BN / 32;
    __shared__ _Float16 As[64 * 256];          // 32 KB, staged once
    __shared__ _Float16 Bs[BN * 64];
    const int bm = blockIdx.y * 64;
    const int bn = blockIdx.x * BN;
    const int tid = threadIdx.x;
    const int lane = tid & 63;
    const int wid = tid >> 6;
    const int wr = wid >> 1, wc = wid & 1;
    const int l15 = lane & 15, lg = lane >> 4;

    {   // ---- LN stage: 4 threads per row, 64 f32 each ----
        int r = tid >> 2, q4 = tid & 3;
        float4 v[16];
        if (bm + r < M) {
            const float4* src = (const float4*)(A + (size_t)(bm + r) * 256 + q4 * 64);
            #pragma unroll
            for (int i = 0; i < 16; ++i) v[i] = src[i];
        } else {
            #pragma unroll
            for (int i = 0; i < 16; ++i) v[i] = make_float4(0.f, 0.f, 0.f, 0.f);
        }
        float s1 = 0.f, s2 = 0.f;
        #pragma unroll
        for (int i = 0; i < 16; ++i) {
            s1 += v[i].x + v[i].y + v[i].z + v[i].w;
            s2 += v[i].x * v[i].x + v[i].y * v[i].y + v[i].z * v[i].z + v[i].w * v[i].w;
        }
        s1 += __shfl_xor(s1, 1); s1 += __shfl_xor(s1, 2);
        s2 += __shfl_xor(s2, 1); s2 += __shfl_xor(s2, 2);
        float mean = s1 * 0.00390625f;
        float var = s2 * 0.00390625f - mean * mean;
        float rs = rsqrtf(var + 1e-6f);
        #pragma unroll
        for (int j = 0; j < 8; ++j) {
            float4 a = v[2 * j], b = v[2 * j + 1];
            f16x8 o = {(_Float16)((a.x - mean) * rs), (_Float16)((a.y - mean) * rs),
                       (_Float16)((a.z - mean) * rs), (_Float16)((a.w - mean) * rs),
                       (_Float16)((b.x - mean) * rs), (_Float16)((b.y - mean) * rs),
                       (_Float16)((b.z - mean) * rs), (_Float16)((b.w - mean) * rs)};
            ((f16x8*)As)[r * 32 + q4 * 8 + (j ^ (r & 7))] = o;
        }
    }

    f32x4 acc[2][NI];
    #pragma unroll
    for (int mi = 0; mi < 2; ++mi)
        #pragma unroll
        for (int ni = 0; ni < NI; ++ni)
            #pragma unroll
            for (int r = 0; r < 4; ++r) acc[mi][ni][r] = 0.f;

    for (int kt = 0; kt < 256; kt += 64) {
        #pragma unroll
        for (int i = 0; i < BN / 32; ++i) {
            int seg = wid * (BN / 32) + i;
            int slot = seg * 64 + lane;
            int row = slot >> 3;
            int chunk = (slot & 7) ^ (row & 7);
            gload16(Bt + (size_t)(bn + row) * 256 + kt + chunk * 8, Bs + seg * 512);
        }
        __syncthreads();
        f16x8 af[2][2], bf[NI][2];
        #pragma unroll
        for (int mi = 0; mi < 2; ++mi) {
            int row = wr * 32 + mi * 16 + l15;
            #pragma unroll
            for (int kk = 0; kk < 2; ++kk)
                af[mi][kk] = ((const f16x8*)As)[row * 32 + (kt >> 3) + ((kk * 4 + lg) ^ (row & 7))];
        }
        #pragma unroll
        for (int ni = 0; ni < NI; ++ni) {
            int row = wc * (BN / 2) + ni * 16 + l15;
            #pragma unroll
            for (int kk = 0; kk < 2; ++kk)
                bf[ni][kk] = ((const f16x8*)Bs)[row * 8 + ((kk * 4 + lg) ^ (row & 7))];
        }
        #pragma unroll
        for (int kk = 0; kk < 2; ++kk)
            #pragma unroll
            for (int mi = 0; mi < 2; ++mi)
                #pragma unroll
                for (int ni = 0; ni < NI; ++ni)
                    acc[mi][ni] = __builtin_amdgcn_mfma_f32_16x16x32_f16(af[mi][kk], bf[ni][kk], acc[mi][ni], 0, 0, 0);
        __syncthreads();
    }

    #pragma unroll
    for (int mi = 0; mi < 2; ++mi) {
        #pragma unroll
        for (int ni = 0; ni < NI; ++ni) {
            int col = bn + wc * (BN / 2) + ni * 16 + l15;
            #pragma unroll
            for (int r = 0; r < 4; ++r) {
                int row = bm + wr * 32 + mi * 16 + lg * 4 + r;
                if (row < M && col < N) {
                    float v = acc[mi][ni][r];
                    if (ACT == 3) {
                        if (col < 1024) {
                            if (BIAS) v += bias[col];
                            Ch[(size_t)row * ldc + col] = (_Float16)gelu_f(v);
                        } else {
                            gout[(size_t)row * 64 + (col - 1024)] = sigmoid_f(v);
                        }
                    } else {
                        Ch[(size_t)row * ldc + col] = (_Float16)v;
                    }
                }
            }
        }
    }
}

// ---------------------------------------------------------------------------
// Batched weight transpose-convert: src fp32 [K][N] -> dst f16 [N][K].
// ---------------------------------------------------------------------------
struct TXT { const float* src; _Float16* dst; int K, N, blk0; };
struct TXA { TXT t[46]; };

__global__ __launch_bounds__(256)
void tconv_k(TXA g)
{
    __shared__ float tile[32][33];
    int b = blockIdx.x;
    int d = 0;
    while (d < 45 && b >= g.t[d + 1].blk0) ++d;
    int local = b - g.t[d].blk0;
    const float* src = g.t[d].src;
    _Float16* dst = g.t[d].dst;
    int K = g.t[d].K, N = g.t[d].N;
    int ntj = N >> 5;
    int ti = local / ntj;
    int tj = local - ti * ntj;
    int tx = threadIdx.x & 31, ty = threadIdx.x >> 5;
    #pragma unroll
    for (int i = 0; i < 4; ++i)
        tile[ty + i * 8][tx] = src[(size_t)(ti * 32 + ty + i * 8) * N + tj * 32 + tx];
    __syncthreads();
    #pragma unroll
    for (int i = 0; i < 4; ++i)
        dst[(size_t)(tj * 32 + ty + i * 8) * K + ti * 32 + tx] = (_Float16)tile[tx][ty + i * 8];
}

// fp32 -> f16 elementwise (8 per thread)
__global__ __launch_bounds__(256)
void cvt_k(const float* __restrict__ src, _Float16* __restrict__ dst, int n8)
{
    int i = blockIdx.x * 256 + threadIdx.x;
    if (i >= n8) return;
    float4 a = ((const float4*)src)[2 * i];
    float4 b = ((const float4*)src)[2 * i + 1];
    f16x8 o = {(_Float16)a.x, (_Float16)a.y, (_Float16)a.z, (_Float16)a.w,
               (_Float16)b.x, (_Float16)b.y, (_Float16)b.z, (_Float16)b.w};
    ((f16x8*)dst)[i] = o;
}

// ---------------------------------------------------------------------------
// kNN — branchless 2-pass threshold, 8 queries x 64 parts per 512-thr block.
// float4 LDS staging; 4-deep unroll; parallel tau/top-16 selection.
// d2 in reference order, contract off (matches numpy top-k boundaries).
// ---------------------------------------------------------------------------
#define CH 1024
#define BUFCAP 192
__global__ __launch_bounds__(512)
void knn_k(const float* __restrict__ coors, int* __restrict__ idxp,
           float* __restrict__ rbfp, float* __restrict__ rup)
{
    #pragma clang fp contract(off)
    __shared__ float4 cf4[CH];
    __shared__ float pm[8][128];
    __shared__ float tauS[8];
    __shared__ int   cnt[8];
    __shared__ float bufD[8][BUFCAP];
    __shared__ int   bufJ[8][BUFCAP];
    __shared__ float selD[8][16];
    __shared__ int   selJ[8][16];

    const int t = threadIdx.x;
    const int qq = t & 7;
    const int part = t >> 3;              // 0..63
    const int n = blockIdx.x * 8 + qq;
    const float qx = coors[n * 3 + 0], qy = coors[n * 3 + 1], qz = coors[n * 3 + 2];

    // ---- pass A: branchless per-part top-2 ----
    float m0 = 3.4e38f, m1 = 3.4e38f;
    for (int cbase = 0; cbase < NPTS; cbase += CH) {
        int cn = min(CH, NPTS - cbase);
        __syncthreads();
        for (int i = t; i < cn; i += 512)
            cf4[i] = make_float4(coors[(cbase + i) * 3 + 0], coors[(cbase + i) * 3 + 1],
                                 coors[(cbase + i) * 3 + 2], 0.f);
        __syncthreads();
        for (int base = 0; base < cn; base += 256) {
            float d2v[4];
            #pragma unroll
            for (int u = 0; u < 4; ++u) {
                int local = base + u * 64 + part;
                float4 c = cf4[local & (CH - 1)];
                float dx = c.x - qx;
                float dy = c.y - qy;
                float dz = c.z - qz;
                float d2 = dx * dx + dy * dy;
                d2 = d2 + dz * dz;
                d2v[u] = (local < cn) ? d2 : 3.4e38f;
            }
            #pragma unroll
            for (int u = 0; u < 4; ++u) {
                float d2 = d2v[u];
                bool l0 = d2 < m0;
                bool l1 = d2 < m1;
                m1 = l0 ? m0 : (l1 ? d2 : m1);
                m0 = l0 ? d2 : m0;
            }
        }
    }
    pm[qq][part * 2] = m0;
    pm[qq][part * 2 + 1] = m1;
    if (t < 8) cnt[t] = 0;
    __syncthreads();

    // ---- tau = 16th smallest of 128 (rank-15 by (value,pos)), parallel ----
    #pragma unroll
    for (int rep = 0; rep < 2; ++rep) {
        int i = part + rep * 64;
        float v = pm[qq][i];
        int c = 0;
        for (int j = 0; j < 128; ++j) {
            float vj = pm[qq][j];
            c += (vj < v || (vj == v && j < i)) ? 1 : 0;
        }
        if (c == 15) tauS[qq] = v;
    }
    __syncthreads();
    const float tau = tauS[qq];

    // ---- pass B: collect qualifying candidates ----
    for (int cbase = 0; cbase < NPTS; cbase += CH) {
        int cn = min(CH, NPTS - cbase);
        __syncthreads();
        for (int i = t; i < cn; i += 512)
            cf4[i] = make_float4(coors[(cbase + i) * 3 + 0], coors[(cbase + i) * 3 + 1],
                                 coors[(cbase + i) * 3 + 2], 0.f);
        __syncthreads();
        for (int base = 0; base < cn; base += 256) {
            #pragma unroll
            for (int u = 0; u < 4; ++u) {
                int local = base + u * 64 + part;
                float4 c = cf4[local & (CH - 1)];
                float dx = c.x - qx;
                float dy = c.y - qy;
                float dz = c.z - qz;
                float d2 = dx * dx + dy * dy;
                d2 = d2 + dz * dz;
                if (local < cn && d2 <= tau) {
                    int pos = atomicAdd(&cnt[qq], 1);
                    if (pos < BUFCAP) { bufD[qq][pos] = d2; bufJ[qq][pos] = cbase + local; }
                }
            }
        }
    }
    __syncthreads();

    // ---- exact top-16: parallel rank-based placement ----
    {
        int c = min(cnt[qq], BUFCAP);
        for (int i = part; i < c; i += 64) {
            float d = bufD[qq][i]; int j = bufJ[qq][i];
            int rank = 0;
            for (int k = 0; k < c; ++k) {
                float dk = bufD[qq][k]; int jk = bufJ[qq][k];
                rank += (dk < d || (dk == d && jk < j)) ? 1 : 0;
            }
            if (rank < 16) { selD[qq][rank] = d; selJ[qq][rank] = j; }
        }
    }
    __syncthreads();

    // ---- outputs: one (query, neighbor) pair per thread (first 128) ----
    if (t < 128) {
        int q = t >> 4, m = t & 15;
        int nn = blockIdx.x * 8 + q;
        int j = selJ[q][m];
        float d2 = selD[q][m];
        float dist = sqrtf(d2 + 1e-6f);
        float rx = coors[j * 3 + 0] - coors[nn * 3 + 0];
        float ry = coors[j * 3 + 1] - coors[nn * 3 + 1];
        float rz = coors[j * 3 + 2] - coors[nn * 3 + 2];
        idxp[nn * 16 + m] = j;
        rup[(nn * 16 + m) * 3 + 0] = rx / dist;
        rup[(nn * 16 + m) * 3 + 1] = ry / dist;
        rup[(nn * 16 + m) * 3 + 2] = rz / dist;
        #pragma unroll
        for (int r = 0; r < 16; ++r) {
            float cc = (4.0f / 15.0f) * r;
            float dd = dist - cc;
            rbfp[(size_t)nn * 256 + m * 16 + r] = expf(-dd * dd * 8.0f);
        }
    }
}

// ---------------------------------------------------------------------------
// Fused attention: 4 nodes per 512-thread block (shared We/Wer LDS).
// P per node: [q|k|v0|vr] f16 (512). V1 per node: 3x128 f16. O0/O1 f16 out.
// ---------------------------------------------------------------------------
__global__ __launch_bounds__(512)
void attn_k(const _Float16* __restrict__ P, const _Float16* __restrict__ V1,
            const float* __restrict__ rbf, const float* __restrict__ ru,
            const int* __restrict__ idx,
            const float* __restrict__ We, const float* __restrict__ Wer,
            _Float16* __restrict__ O0, _Float16* __restrict__ O1)
{
    const int t = threadIdx.x;
    const int sub = t >> 7;
    const int hd = t & 127;
    const int h = hd >> 5;
    const int n = blockIdx.x * 4 + sub;
    __shared__ float WeS[16][128], WerS[16][128];
    __shared__ float rbfS[4][16][16];
    __shared__ float ruS[4][16][4];
    __shared__ int   idxS[4][16];
    __shared__ float logitsS[4][4][16];
    __shared__ float attnS[4][4][16];

    #pragma unroll
    for (int i = 0; i < 4; ++i) {
        int ix = t + i * 512;
        WeS[ix >> 7][ix & 127]  = We[ix];
        WerS[ix >> 7][ix & 127] = Wer[ix];
    }
    ((float*)rbfS[sub])[hd]       = rbf[(size_t)n * 256 + hd];
    ((float*)rbfS[sub])[hd + 128] = rbf[(size_t)n * 256 + 128 + hd];
    if (hd < 16) idxS[sub][hd] = idx[n * 16 + hd];
    if (hd < 48) ruS[sub][hd / 3][hd % 3] = ru[n * 48 + hd];
    float q = (float)P[(size_t)n * 512 + hd];
    __syncthreads();

    #pragma unroll 4
    for (int k = 0; k < 16; ++k) {
        int j = idxS[sub][k];
        float kv = (float)P[(size_t)j * 512 + 128 + hd];
        float racc = 0.f;
        #pragma unroll
        for (int r = 0; r < 16; ++r) racc += rbfS[sub][k][r] * WeS[r][hd];
        kv += racc;
        float prod = q * kv;
        prod += __shfl_xor(prod, 1);
        prod += __shfl_xor(prod, 2);
        prod += __shfl_xor(prod, 4);
        prod += __shfl_xor(prod, 8);
        prod += __shfl_xor(prod, 16);
        if ((hd & 31) == 0) logitsS[sub][h][k] = prod * 0.17677669529663687f;
    }
    __syncthreads();

    {
        float mx = -1e30f;
        #pragma unroll
        for (int k = 0; k < 16; ++k) mx = fmaxf(mx, logitsS[sub][h][k]);
        float aw[16]; float s = 0.f;
        #pragma unroll
        for (int k = 0; k < 16; ++k) { aw[k] = expf(logitsS[sub][h][k] - mx); s += aw[k]; }
        float inv = 1.f / s;
        if ((hd & 31) == 0) {
            #pragma unroll
            for (int k = 0; k < 16; ++k) attnS[sub][h][k] = aw[k] * inv;
        }
    }
    __syncthreads();

    float o0 = 0.f, o1x = 0.f, o1y = 0.f, o1z = 0.f;
    #pragma unroll 4
    for (int k = 0; k < 16; ++k) {
        int j = idxS[sub][k];
        float a = attnS[sub][h][k];
        const _Float16* pj = P + (size_t)j * 512;
        float v0 = (float)pj[256 + hd];
        float ge = (float)pj[384 + hd];
        float racc = 0.f;
        #pragma unroll
        for (int r = 0; r < 16; ++r) racc += rbfS[sub][k][r] * WerS[r][hd];
        ge += racc;
        const _Float16* vj = V1 + (size_t)j * 384;
        o0  += a * v0;
        o1x += a * ((float)vj[hd]       + ge * ruS[sub][k][0]);
        o1y += a * ((float)vj[128 + hd] + ge * ruS[sub][k][1]);
        o1z += a * ((float)vj[256 + hd] + ge * ruS[sub][k][2]);
    }
    O0[(size_t)n * 128 + hd] = (_Float16)o0;
    _Float16* o1p = O1 + (size_t)n * 384;
    o1p[hd] = (_Float16)o1x; o1p[128 + hd] = (_Float16)o1y; o1p[256 + hd] = (_Float16)o1z;
}

// ---------------------------------------------------------------------------
__global__ __launch_bounds__(256)
void vecout_k(const float* __restrict__ f1, const float* __restrict__ wv,
              float* __restrict__ out2)
{
    int row = blockIdx.x * 256 + threadIdx.x;
    if (row >= NPTS * 3) return;
    const float4* fr = (const float4*)(f1 + (size_t)row * 64);
    const float4* w4 = (const float4*)wv;
    float s = 0.f;
    #pragma unroll
    for (int c = 0; c < 16; ++c) {
        float4 a = fr[c], b = w4[c];
        s += a.x * b.x + a.y * b.y + a.z * b.z + a.w * b.w;
    }
    out2[row] = s;
}

// ---------------------------------------------------------------------------
extern "C" void kernel_launch(void* const* d_in, const int* in_sizes, int n_in,
                              void* d_out, int out_size, void* d_ws, size_t ws_size,
                              hipStream_t stream)
{
    (void)in_sizes; (void)n_in; (void)out_size; (void)ws_size;
    const float* feats = (const float*)d_in[0];
    const float* coors = (const float*)d_in[1];
    const float* Wemb = (const float*)d_in[3];
    const float* Wq   = (const float*)d_in[4];
    const float* Wk   = (const float*)d_in[5];
    const float* Wv0  = (const float*)d_in[6];
    const float* Wvr  = (const float*)d_in[7];
    const float* We   = (const float*)d_in[8];
    const float* Wer  = (const float*)d_in[9];
    const float* Wv1  = (const float*)d_in[10];
    const float* Wo0  = (const float*)d_in[11];
    const float* Wo1  = (const float*)d_in[12];
    const float* Wf1  = (const float*)d_in[13];
    const float* bf1  = (const float*)d_in[14];
    const float* Wf2  = (const float*)d_in[15];
    const float* bf2  = (const float*)d_in[16];
    const float* Wg   = (const float*)d_in[17];
    const float* Wvff = (const float*)d_in[18];
    const float* Ws   = (const float*)d_in[19];
    const float* bs   = (const float*)d_in[20];
    const float* wv   = (const float*)d_in[21];
    float* out = (float*)d_out;

    char* ws = (char*)d_ws;
    size_t off = 0;
    auto carve = [&](size_t bytes) -> char* {
        char* p = ws + off;
        off += (bytes + 255) & ~(size_t)255;
        return p;
    };
    int*      idxp   = (int*)      carve((size_t)NPTS * 16 * 4);
    float*    rbfp   = (float*)    carve((size_t)NPTS * 256 * 4);
    float*    rup    = (float*)    carve((size_t)NPTS * 48 * 4);
    float*    f0     = (float*)    carve((size_t)NPTS * 256 * 4);
    float*    f1     = (float*)    carve((size_t)NPTS * 192 * 4);
    float*    gt     = (float*)    carve((size_t)NPTS * 64 * 4);
    _Float16* f0h    = (_Float16*) carve((size_t)NPTS * 256 * 2);
    _Float16* f1h    = (_Float16*) carve((size_t)NPTS * 192 * 2);
    _Float16* O1h    = (_Float16*) carve((size_t)NPTS * 384 * 2);
    _Float16* featsh = (_Float16*) carve((size_t)NPTS * 256 * 2);
    // Ph + V1h + O0h contiguous (10.24 + 7.68 + 2.56 MB = 20.48 MB);
    // Hbh (10000 x 1024 f16 = 20.48 MB) aliases them (all dead by FFN time).
    _Float16* Ph     = (_Float16*) carve((size_t)NPTS * 512 * 2);
    _Float16* V1h    = (_Float16*) carve((size_t)NPTS * 384 * 2);
    _Float16* O0h    = (_Float16*) carve((size_t)NPTS * 128 * 2);
    _Float16* Hbh    = Ph;
    _Float16* WembT  = (_Float16*) carve(65536 * 2);
    _Float16* WqkvrT = (_Float16*) carve(4 * 131072 * 2);
    _Float16* Wv1T   = (_Float16*) carve(4 * 8192 * 2);
    _Float16* Wo0T   = (_Float16*) carve(4 * 32768 * 2);
    _Float16* Wo1T   = (_Float16*) carve(4 * 8192 * 2);
    _Float16* WfgT   = (_Float16*) carve(4 * 278528 * 2);   // [Wf1(1024) ; Wg(64)] x 256
    _Float16* Wf2T   = (_Float16*) carve(4 * 262144 * 2);
    _Float16* WvffT  = (_Float16*) carve(4 * 4096 * 2);
    _Float16* WsT    = (_Float16*) carve(65536 * 2);

    // ---- weight transpose-convert (46 descriptors, one launch) ----
    TXA ta;
    int blk = 0, di = 0;
    auto addt = [&](const float* s, _Float16* d, int Ks, int Ns) {
        ta.t[di].src = s; ta.t[di].dst = d; ta.t[di].K = Ks; ta.t[di].N = Ns;
        ta.t[di].blk0 = blk; blk += (Ks / 32) * (Ns / 32); ++di;
    };
    addt(Wemb, WembT, 256, 256);
    for (int l = 0; l < 4; ++l) {
        addt(Wq  + l * 32768, WqkvrT + (size_t)l * 131072 +     0, 256, 128);
        addt(Wk  + l * 32768, WqkvrT + (size_t)l * 131072 + 32768, 256, 128);
        addt(Wv0 + l * 32768, WqkvrT + (size_t)l * 131072 + 65536, 256, 128);
        addt(Wvr + l * 32768, WqkvrT + (size_t)l * 131072 + 98304, 256, 128);
    }
    for (int l = 0; l < 4; ++l) addt(Wv1  + l * 8192,   Wv1T  + l * 8192,   64, 128);
    for (int l = 0; l < 4; ++l) addt(Wo0  + l * 32768,  Wo0T  + l * 32768,  128, 256);
    for (int l = 0; l < 4; ++l) addt(Wo1  + l * 8192,   Wo1T  + l * 8192,   128, 64);
    for (int l = 0; l < 4; ++l) {
        addt(Wf1 + l * 262144, WfgT + (size_t)l * 278528,          256, 1024);
        addt(Wg  + l * 16384,  WfgT + (size_t)l * 278528 + 262144, 256, 64);
    }
    for (int l = 0; l < 4; ++l) addt(Wf2  + l * 262144, Wf2T  + l * 262144, 1024, 256);
    for (int l = 0; l < 4; ++l) addt(Wvff + l * 4096,   WvffT + l * 4096,   64, 64);
    addt(Ws, WsT, 256, 256);
    tconv_k<<<blk, 256, 0, stream>>>(ta);

    cvt_k<<<1250, 256, 0, stream>>>(feats, featsh, NPTS * 256 / 8);
    knn_k<<<1250, 512, 0, stream>>>(coors, idxp, rbfp, rup);

    // f0 = feats @ Wemb
    hgemm_k<0,false,false,false,0,64><<<dim3(4,157),256,0,stream>>>(featsh,256,WembT,nullptr,nullptr,f0,nullptr,256,NPTS,256,256);
    hipMemsetAsync(f1, 0, (size_t)NPTS * 192 * 4, stream);
    hipMemsetAsync(f1h, 0, (size_t)NPTS * 192 * 2, stream);

    for (int l = 0; l < 4; ++l) {
        // Ph = f16( LN(f0) @ [Wq|Wk|Wv0|Wvr] )   (LN fused)
        lngemm_k<0,false,128><<<dim3(4,157),256,0,stream>>>(f0,WqkvrT+(size_t)l*131072,nullptr,nullptr,Ph,512,NPTS,512);
        // V1h = f16( f1 @ Wv1 )
        hgemm_k<0,false,false,false,1,64><<<dim3(2,469),256,0,stream>>>(f1h,64,Wv1T+l*8192,nullptr,nullptr,nullptr,V1h,128,NPTS*3,128,64);
        attn_k<<<2500,512,0,stream>>>(Ph, V1h, rbfp, rup, idxp, We + l*2048, Wer + l*2048, O0h, O1h);
        // f0 += O0 @ Wo0
        hgemm_k<0,true,false,false,0,64><<<dim3(4,157),256,0,stream>>>(O0h,128,Wo0T+l*32768,nullptr,nullptr,f0,nullptr,256,NPTS,256,128);
        // f1 += O1 @ Wo1 (+ f16 mirror)
        hgemm_k<0,true,false,false,2,64><<<dim3(1,469),256,0,stream>>>(O1h,128,Wo1T+l*8192,nullptr,nullptr,f1,f1h,64,NPTS*3,64,128);
        // Hb = gelu(LN(f0) @ Wf1 + bf1) f16; gate = sigmoid(LN(f0) @ Wg) — LN fused
        lngemm_k<3,true,128><<<dim3(9,157),256,0,stream>>>(f0,WfgT+(size_t)l*278528,bf1+l*1024,gt,Hbh,1024,NPTS,1088);
        // f0 += Hb @ Wf2 + bf2 (last layer also writes f0h)
        if (l < 3)
            hgemm_k<0,true,true,false,0,64><<<dim3(4,157),256,0,stream>>>(Hbh,1024,Wf2T+(size_t)l*262144,bf2+l*256,nullptr,f0,nullptr,256,NPTS,256,1024);
        else
            hgemm_k<0,true,true,false,2,64><<<dim3(4,157),256,0,stream>>>(Hbh,1024,Wf2T+(size_t)l*262144,bf2+l*256,nullptr,f0,f0h,256,NPTS,256,1024);
        // f1 += (f1 @ Wvff) * gate (+ f16 mirror)
        hgemm_k<0,true,false,true,2,64><<<dim3(1,469),256,0,stream>>>(f1h,64,WvffT+l*4096,nullptr,gt,f1,f1h,64,NPTS*3,64,64);
    }

    // pred_scalar = f0 @ Ws + bs
    hgemm_k<0,false,true,false,0,64><<<dim3(4,157),256,0,stream>>>(f0h,256,WsT,bs,nullptr,out,nullptr,256,NPTS,256,256);
    // pred_vector
    vecout_k<<<118,256,0,stream>>>(f1, wv, out + (size_t)NPTS * 256);
}